// Round 8
// baseline (389.653 us; speedup 1.0000x reference)
//
#include <hip/hip_runtime.h>
#include <cstdint>

#define N_NODES 50000
#define N_PAD 50048  // 391 * 128
#define N_EDGES 400000
#define IN_DIM 512
#define HID 512
#define HID2 256
#define NUM_GRAPHS 500
#define SCAN_BLOCKS 196  // ceil(50000/256)

typedef unsigned short u16;
typedef short s8v __attribute__((ext_vector_type(8)));    // 8 bf16 for MFMA A/B
typedef float f4v __attribute__((ext_vector_type(4)));    // MFMA C/D
typedef u16 u16x8 __attribute__((ext_vector_type(8)));
typedef u16 u16x4 __attribute__((ext_vector_type(4)));

__device__ __forceinline__ u16 f2bf(float f) {
  union { float f; uint32_t u; } c;
  c.f = f;
  const uint32_t u = c.u;
  return (u16)((u + 0x7fffu + ((u >> 16) & 1u)) >> 16);  // RNE
}
__device__ __forceinline__ float bf2f(u16 v) {
  union { uint32_t u; float f; } c;
  c.u = ((uint32_t)v) << 16;
  return c.f;
}

// global -> LDS async, 16B per lane. LDS dest = wave-uniform base + lane*16.
__device__ __forceinline__ void gload16(const void* g, void* l) {
  __builtin_amdgcn_global_load_lds(
      (const __attribute__((address_space(1))) void*)(uintptr_t)g,
      (__attribute__((address_space(3))) void*)(uint32_t)(uintptr_t)l, 16, 0, 0);
}

// bijective chunked XCD swizzle (m204): contiguous id-range per XCD
__device__ __forceinline__ int xcd_swizzle(int orig, int nwg) {
  const int q = nwg >> 3, rr = nwg & 7;
  const int xcd = orig & 7, idx = orig >> 3;
  return (xcd < rr ? xcd * (q + 1) : rr * (q + 1) + (xcd - rr) * q) + idx;
}

// ---------------------------------------------------------------------------
// weight fp32 -> bf16 (x conversion is fused into gemm_mfma<AF32=1>)
// ---------------------------------------------------------------------------
__global__ __launch_bounds__(256) void cvt_weights(const float* __restrict__ W1l,
                                                   const float* __restrict__ W1r,
                                                   const float* __restrict__ W2l,
                                                   const float* __restrict__ W2r,
                                                   u16* __restrict__ Wc1,
                                                   u16* __restrict__ Wc2) {
  const int i = blockIdx.x * 256 + threadIdx.x;
  const float* src;
  u16* dstp;
  int l;
  if (i < 32768)      { src = W1l; dstp = Wc1;          l = i; }
  else if (i < 65536) { src = W1r; dstp = Wc1 + 262144; l = i - 32768; }
  else if (i < 81920) { src = W2l; dstp = Wc2;          l = i - 65536; }
  else                { src = W2r; dstp = Wc2 + 131072; l = i - 81920; }
  const float4 a = ((const float4*)src)[2 * l];
  const float4 b = ((const float4*)src)[2 * l + 1];
  u16x8 o;
  o[0] = f2bf(a.x); o[1] = f2bf(a.y); o[2] = f2bf(a.z); o[3] = f2bf(a.w);
  o[4] = f2bf(b.x); o[5] = f2bf(b.y); o[6] = f2bf(b.z); o[7] = f2bf(b.w);
  ((u16x8*)dstp)[l] = o;
}

// ---------------------------------------------------------------------------
// bf16 MFMA GEMM: [N_PAD,K] x [NX*128,K]^T. 1D grid, N-fast + XCD chunk
// swizzle. Output split: n-tiles [0,NXH) -> CT, rest -> CR (ld = NXH*128).
// 128x128 tile, BK=32, 256 thr (4 waves 2x2), 4x4 frags of 16x16x32.
// 2-deep pipeline, counted vmcnt (T4). K-chunk swizzle (T2, both-sides).
// AF32=1: A is fp32 (x) — reg-staged: float4 loads issued at iteration TOP
// (latency hides under MFMA phase, T14), cvt+ds_write after the barrier with
// the same chunk permutation; B stays on global_load_lds. In-order vmcnt
// retirement: the compiler's wait before the cvt also drains B(t+1).
// Rows clamped to N_NODES-1 (x has exactly N_NODES rows; pad rows dont-care).
// ---------------------------------------------------------------------------
template <int K, int NXL2, int NXH, int AF32>
__global__ __launch_bounds__(256) void gemm_mfma(const u16* __restrict__ A,
                                                 const float* __restrict__ Af,
                                                 const u16* __restrict__ B,
                                                 u16* __restrict__ CT,
                                                 u16* __restrict__ CR,
                                                 int nwg) {
  __shared__ __align__(16) u16 As[2][128 * 32];
  __shared__ __align__(16) u16 Bs[2][128 * 32];
  const int id = xcd_swizzle(blockIdx.x, nwg);
  const int bx = id & ((1 << NXL2) - 1);   // N tile (fast)
  const int by = id >> NXL2;               // M tile
  const int tid = threadIdx.x;
  const int lane = tid & 63;
  const int wave = tid >> 6;
  const int wr = (wave >> 1) * 64;
  const int wc = (wave & 1) * 64;
  const int fr = lane & 15;
  const int fq = lane >> 4;
  const size_t bm = (size_t)by * 128;
  const size_t bn = (size_t)bx * 128;

  // staging geometry: linear LDS dest slot (tid&3); global chunk pre-swizzled
  const int r0 = tid >> 2;                         // 0..63
  const int cg = ((tid & 3) ^ ((tid >> 3) & 3));   // swizzled k-chunk index
  const u16* gB = B + (bn + r0) * K + cg * 8;
  const int lofs = r0 * 32 + (tid & 3) * 8;        // linear dest (u16 units)
  constexpr int nt = K >> 5;

  // A addressing
  const u16* gA = nullptr;
  const float* gAf0 = nullptr;
  const float* gAf1 = nullptr;
  size_t rstepA = 0;
  if (AF32) {
    const int ar0 = min((int)bm + r0, N_NODES - 1);
    const int ar1 = min((int)bm + r0 + 64, N_NODES - 1);
    gAf0 = Af + (size_t)ar0 * K + cg * 8;
    gAf1 = Af + (size_t)ar1 * K + cg * 8;
  } else {
    gA = A + (bm + r0) * K + cg * 8;
    rstepA = (size_t)64 * K;
  }
  const size_t rstepB = (size_t)64 * K;

  auto stageB = [&](int b, int kt) {
    const int k0 = kt << 5;
    gload16(gB + k0, &Bs[b][lofs]);
    gload16(gB + rstepB + k0, &Bs[b][lofs + 64 * 32]);
  };
  auto stageA_lds = [&](int b, int kt) {  // !AF32 path
    const int k0 = kt << 5;
    gload16(gA + k0, &As[b][lofs]);
    gload16(gA + rstepA + k0, &As[b][lofs + 64 * 32]);
  };
  auto writeA = [&](int b, const float4& v0, const float4& v1,
                    const float4& v2, const float4& v3) {
    u16x8 w0, w1;
    w0[0] = f2bf(v0.x); w0[1] = f2bf(v0.y); w0[2] = f2bf(v0.z); w0[3] = f2bf(v0.w);
    w0[4] = f2bf(v1.x); w0[5] = f2bf(v1.y); w0[6] = f2bf(v1.z); w0[7] = f2bf(v1.w);
    w1[0] = f2bf(v2.x); w1[1] = f2bf(v2.y); w1[2] = f2bf(v2.z); w1[3] = f2bf(v2.w);
    w1[4] = f2bf(v3.x); w1[5] = f2bf(v3.y); w1[6] = f2bf(v3.z); w1[7] = f2bf(v3.w);
    *(u16x8*)(&As[b][lofs]) = w0;
    *(u16x8*)(&As[b][lofs + 64 * 32]) = w1;
  };

  f4v acc[4][4];
#pragma unroll
  for (int m = 0; m < 4; ++m)
#pragma unroll
    for (int n = 0; n < 4; ++n)
      acc[m][n] = f4v{0.f, 0.f, 0.f, 0.f};

  // read-side swizzle: slot = fq ^ kx, kx = (fr>>1)&3 (row-pair parity)
  const int kx = (fr >> 1) & 3;
  const int slot8 = (fq ^ kx) * 8;

  // ---- prologue: tiles 0,1 staged ----
  if (AF32) {
    {
      float4 v0 = *(const float4*)(gAf0 + 0), v1 = *(const float4*)(gAf0 + 4);
      float4 v2 = *(const float4*)(gAf1 + 0), v3 = *(const float4*)(gAf1 + 4);
      writeA(0, v0, v1, v2, v3);
    }
    stageB(0, 0);
    {
      float4 v0 = *(const float4*)(gAf0 + 32), v1 = *(const float4*)(gAf0 + 36);
      float4 v2 = *(const float4*)(gAf1 + 32), v3 = *(const float4*)(gAf1 + 36);
      writeA(1, v0, v1, v2, v3);  // compiler vmem-wait here also drains B(0)
    }
    stageB(1, 1);
    asm volatile("s_waitcnt lgkmcnt(0)" ::: "memory");
  } else {
    stageA_lds(0, 0); stageB(0, 0);
    stageA_lds(1, 1); stageB(1, 1);
    asm volatile("s_waitcnt vmcnt(4)" ::: "memory");
  }
  __builtin_amdgcn_s_barrier();

  for (int t = 0; t < nt; ++t) {
    // issue next-next A loads early (AF32): latency hides under MFMA phase
    float4 av0, av1, av2, av3;
    if (AF32 && t + 2 < nt) {
      const int k0 = (t + 2) << 5;
      av0 = *(const float4*)(gAf0 + k0);
      av1 = *(const float4*)(gAf0 + k0 + 4);
      av2 = *(const float4*)(gAf1 + k0);
      av3 = *(const float4*)(gAf1 + k0 + 4);
    }
    const u16* curA = As[t & 1];
    const u16* curB = Bs[t & 1];
    s8v af[4], bf_[4];
#pragma unroll
    for (int m = 0; m < 4; ++m)
      af[m] = *(const s8v*)(curA + (wr + m * 16 + fr) * 32 + slot8);
#pragma unroll
    for (int n = 0; n < 4; ++n)
      bf_[n] = *(const s8v*)(curB + (wc + n * 16 + fr) * 32 + slot8);
#pragma unroll
    for (int m = 0; m < 4; ++m)
#pragma unroll
      for (int n = 0; n < 4; ++n)
        acc[m][n] = __builtin_amdgcn_mfma_f32_16x16x32_bf16(bf_[n], af[m],
                                                            acc[m][n], 0, 0, 0);
    if (t == nt - 1) break;
    __builtin_amdgcn_s_barrier();  // all waves done ds_reading buf[t&1]
    if (t + 2 < nt) {
      if (AF32) {
        stageB(t & 1, t + 2);            // issue B first (stays in flight)
        writeA(t & 1, av0, av1, av2, av3);  // compiler wait drains B(t+1)+av
        asm volatile("s_waitcnt lgkmcnt(0)" ::: "memory");
      } else {
        stageA_lds(t & 1, t + 2);
        stageB(t & 1, t + 2);
        asm volatile("s_waitcnt vmcnt(4)" ::: "memory");
      }
    } else {
      asm volatile("s_waitcnt vmcnt(0)" ::: "memory");
    }
    __builtin_amdgcn_s_barrier();
  }

  // epilogue (swapped layout): row = bm+wr+m*16+fr, col = cn0+n*16+fq*4+i
  u16* Cb = (bx < NXH) ? CT : CR;
  constexpr int ldc = NXH * 128;
  const size_t cn0 = (size_t)(bx - (bx >= NXH ? NXH : 0)) * 128 + wc;
#pragma unroll
  for (int m = 0; m < 4; ++m) {
    const size_t row = bm + wr + m * 16 + fr;
#pragma unroll
    for (int n = 0; n < 4; ++n) {
      const size_t col = cn0 + n * 16 + fq * 4;
      u16x4 p;
#pragma unroll
      for (int i = 0; i < 4; ++i) p[i] = f2bf(acc[m][n][i]);
      *(u16x4*)(Cb + row * ldc + col) = p;
    }
  }
}

// ---------------------------------------------------------------------------
// CSR build: histogram + hierarchical scan + cursor fill
// ---------------------------------------------------------------------------
__global__ void deg_hist(const int* __restrict__ dst, int* __restrict__ degi, int nE) {
  const int e = blockIdx.x * 256 + threadIdx.x;
  if (e < nE) atomicAdd(&degi[dst[e]], 1);
}

__device__ __forceinline__ int block_scan_excl(int v, int* total_out) {
  const int lane = threadIdx.x & 63;
  const int wid = threadIdx.x >> 6;
  int s = v;
#pragma unroll
  for (int off = 1; off < 64; off <<= 1) {
    const int t = __shfl_up(s, off);
    if (lane >= off) s += t;
  }
  __shared__ int wsum[4];
  if (lane == 63) wsum[wid] = s;
  __syncthreads();
  int base = 0;
#pragma unroll
  for (int w = 0; w < 4; ++w)
    if (w < wid) base += wsum[w];
  *total_out = wsum[0] + wsum[1] + wsum[2] + wsum[3];
  return base + s - v;
}

__global__ __launch_bounds__(256) void scan_blocks(const int* __restrict__ degi,
                                                   int* __restrict__ offs,
                                                   int* __restrict__ bsum, int n) {
  const int gid = blockIdx.x * 256 + threadIdx.x;
  const int v = (gid < n) ? degi[gid] : 0;
  int total;
  const int excl = block_scan_excl(v, &total);
  if (gid < n) offs[gid] = excl;
  if (threadIdx.x == 0) bsum[blockIdx.x] = total;
}

__global__ __launch_bounds__(256) void scan_bsums(int* __restrict__ bsum, int nb) {
  const int v = (threadIdx.x < nb) ? bsum[threadIdx.x] : 0;
  int total;
  const int excl = block_scan_excl(v, &total);
  if (threadIdx.x < nb) bsum[threadIdx.x] = excl;
}

__global__ __launch_bounds__(256) void add_base(int* __restrict__ offs,
                                                const int* __restrict__ bsum,
                                                int n, int nE) {
  const int gid = blockIdx.x * 256 + threadIdx.x;
  if (gid < n) offs[gid] += bsum[blockIdx.x];
  if (gid == 0) offs[n] = nE;
}

__global__ void fill_csr(const int* __restrict__ src, const int* __restrict__ dst,
                         const int* __restrict__ offs, int* __restrict__ cursor,
                         int* __restrict__ sorted_src, int nE) {
  const int e = blockIdx.x * 256 + threadIdx.x;
  if (e < nE) {
    const int d = dst[e];
    const int pos = offs[d] + atomicAdd(&cursor[d], 1);
    sorted_src[pos] = src[e];
  }
}

// ---------------------------------------------------------------------------
// h[n] = relu( mean_{e in CSR(n)} t[src_e] + bias + r[n] ), bf16 in, compact
// ld = D. D/8 lanes per node; 8-deep independent-load batches (avg deg = 8).
// ---------------------------------------------------------------------------
template <int D, int OUTF32>
__global__ __launch_bounds__(256) void gather_combine(
    const u16* __restrict__ t, const u16* __restrict__ r,
    const float* __restrict__ bias, const int* __restrict__ offs,
    const int* __restrict__ ssrc, void* __restrict__ hout) {
  constexpr int LPN = D / 8;
  const int node = (int)((blockIdx.x * 256u + threadIdx.x) / LPN);
  if (node >= N_NODES) return;
  const int o = (int)(threadIdx.x % LPN) * 8;
  const int beg = offs[node], end = offs[node + 1];
  float a[8] = {0.f, 0.f, 0.f, 0.f, 0.f, 0.f, 0.f, 0.f};
  int e = beg;
  for (; e + 7 < end; e += 8) {
    u16x8 v[8];
#pragma unroll
    for (int q = 0; q < 8; ++q)
      v[q] = *(const u16x8*)(t + (size_t)ssrc[e + q] * D + o);
#pragma unroll
    for (int j = 0; j < 8; ++j)
      a[j] += ((bf2f(v[0][j]) + bf2f(v[1][j])) + (bf2f(v[2][j]) + bf2f(v[3][j]))) +
              ((bf2f(v[4][j]) + bf2f(v[5][j])) + (bf2f(v[6][j]) + bf2f(v[7][j])));
  }
  if (e + 3 < end) {
    u16x8 v[4];
#pragma unroll
    for (int q = 0; q < 4; ++q)
      v[q] = *(const u16x8*)(t + (size_t)ssrc[e + q] * D + o);
#pragma unroll
    for (int j = 0; j < 8; ++j)
      a[j] += (bf2f(v[0][j]) + bf2f(v[1][j])) + (bf2f(v[2][j]) + bf2f(v[3][j]));
    e += 4;
  }
  for (; e < end; ++e) {
    const u16x8 v0 = *(const u16x8*)(t + (size_t)ssrc[e] * D + o);
#pragma unroll
    for (int j = 0; j < 8; ++j) a[j] += bf2f(v0[j]);
  }
  const float invd = 1.0f / fmaxf((float)(end - beg), 1.0f);
  const u16x8 rv = *(const u16x8*)(r + (size_t)node * D + o);
  float hv[8];
#pragma unroll
  for (int j = 0; j < 8; ++j)
    hv[j] = fmaxf(fmaf(a[j], invd, bias[o + j] + bf2f(rv[j])), 0.f);
  if (OUTF32) {
    float* hp = (float*)hout + (size_t)node * D + o;
    *(float4*)hp = make_float4(hv[0], hv[1], hv[2], hv[3]);
    *(float4*)(hp + 4) = make_float4(hv[4], hv[5], hv[6], hv[7]);
  } else {
    u16x8 ov;
#pragma unroll
    for (int j = 0; j < 8; ++j) ov[j] = f2bf(hv[j]);
    *(u16x8*)((u16*)hout + (size_t)node * D + o) = ov;
  }
}

// ---------------------------------------------------------------------------
// Fused pool + FC + log_softmax (batch sorted -> contiguous node ranges)
// h is bf16 [N_NODES, HID2]
// ---------------------------------------------------------------------------
__global__ __launch_bounds__(256) void pool_final(const u16* __restrict__ h,
                                                  const int* __restrict__ batch,
                                                  const float* __restrict__ Wfc,
                                                  const float* __restrict__ bfc,
                                                  float* __restrict__ out, int nNodes) {
  const int g = blockIdx.x;
  __shared__ int sbeg, send;
  if (threadIdx.x == 0) {
    int lo = 0, hi = nNodes;
    while (lo < hi) { const int mid = (lo + hi) >> 1; if (batch[mid] < g) lo = mid + 1; else hi = mid; }
    sbeg = lo;
    hi = nNodes;
    while (lo < hi) { const int mid = (lo + hi) >> 1; if (batch[mid] < g + 1) lo = mid + 1; else hi = mid; }
    send = lo;
  }
  __syncthreads();
  const int t = threadIdx.x;
  float s = 0.f;
  for (int row = sbeg; row < send; ++row) s += bf2f(h[(size_t)row * HID2 + t]);
  const float cnt = fmaxf((float)(send - sbeg), 1.0f);
  const float p = s / cnt;
  float d0 = p * Wfc[t];
  float d1 = p * Wfc[HID2 + t];
#pragma unroll
  for (int off = 32; off > 0; off >>= 1) {
    d0 += __shfl_down(d0, off);
    d1 += __shfl_down(d1, off);
  }
  __shared__ float r0[4], r1[4];
  const int wid = t >> 6, lane = t & 63;
  if (lane == 0) { r0[wid] = d0; r1[wid] = d1; }
  __syncthreads();
  if (t == 0) {
    const float l0 = r0[0] + r0[1] + r0[2] + r0[3] + bfc[0];
    const float l1 = r1[0] + r1[1] + r1[2] + r1[3] + bfc[1];
    const float m = fmaxf(l0, l1);
    const float lse = m + logf(expf(l0 - m) + expf(l1 - m));
    out[g * 2 + 0] = l0 - lse;
    out[g * 2 + 1] = l1 - lse;
  }
}

extern "C" void kernel_launch(void* const* d_in, const int* in_sizes, int n_in,
                              void* d_out, int out_size, void* d_ws, size_t ws_size,
                              hipStream_t stream) {
  (void)in_sizes; (void)n_in; (void)out_size; (void)ws_size;
  const float* x   = (const float*)d_in[0];
  const int* eidx  = (const int*)d_in[1];
  const int* batch = (const int*)d_in[2];
  const float* W1l = (const float*)d_in[3];
  const float* b1  = (const float*)d_in[4];
  const float* W1r = (const float*)d_in[5];
  const float* W2l = (const float*)d_in[6];
  const float* b2  = (const float*)d_in[7];
  const float* W2r = (const float*)d_in[8];
  const float* Wfc = (const float*)d_in[9];
  const float* bfc = (const float*)d_in[10];
  float* out = (float*)d_out;
  const int* src = eidx;
  const int* dst = eidx + N_EDGES;

  char* ws = (char*)d_ws;
  size_t off = 0;
  auto alloc = [&](size_t bytes) {
    char* p = ws + off;
    off += (bytes + 255) & ~(size_t)255;
    return p;
  };
  u16* bufT = (u16*)alloc((size_t)N_PAD * 512 * 2);  // t1; reused as t2 (ld 256)
  u16* bufR = (u16*)alloc((size_t)N_PAD * 512 * 2);  // r1; reused as r2 (ld 256)
  u16* h1   = (u16*)alloc((size_t)N_PAD * 512 * 2);
  u16* h2   = (u16*)alloc((size_t)N_NODES * 256 * 2);
  u16* Wc1  = (u16*)alloc((size_t)1024 * 512 * 2);
  u16* Wc2  = (u16*)alloc((size_t)512 * 512 * 2);
  int* degi   = (int*)alloc((size_t)N_NODES * 4);    // 200192 B reserved
  int* cursor = (int*)alloc((size_t)N_NODES * 4);    // adjacent to degi
  int* offs       = (int*)alloc((size_t)(N_NODES + 1) * 4);
  int* sorted_src = (int*)alloc((size_t)N_EDGES * 4);
  int* bsum       = (int*)alloc((size_t)SCAN_BLOCKS * 4);

  // ---- CSR build ----
  hipMemsetAsync(degi, 0, 200192 + (size_t)N_NODES * 4, stream);
  deg_hist<<<(N_EDGES + 255) / 256, 256, 0, stream>>>(dst, degi, N_EDGES);
  scan_blocks<<<SCAN_BLOCKS, 256, 0, stream>>>(degi, offs, bsum, N_NODES);
  scan_bsums<<<1, 256, 0, stream>>>(bsum, SCAN_BLOCKS);
  add_base<<<SCAN_BLOCKS, 256, 0, stream>>>(offs, bsum, N_NODES, N_EDGES);
  fill_csr<<<(N_EDGES + 255) / 256, 256, 0, stream>>>(src, dst, offs, cursor,
                                                      sorted_src, N_EDGES);

  // ---- weight conversions (x conversion fused into GEMM1) ----
  cvt_weights<<<384, 256, 0, stream>>>(W1l, W1r, W2l, W2r, Wc1, Wc2);

  // ---- layer 1: fp32 x [N_PAD,512] x [1024,512]^T -> t1 | r1 ----
  {
    const int nwg = (N_PAD / 128) * 8;  // 3128
    gemm_mfma<IN_DIM, 3, 4, 1><<<nwg, 256, 0, stream>>>(nullptr, x, Wc1,
                                                        bufT, bufR, nwg);
  }
  gather_combine<HID, 0><<<(N_NODES + 3) / 4, 256, 0, stream>>>(
      bufT, bufR, b1, offs, sorted_src, h1);

  // ---- layer 2: [N_PAD,512] x [512,512]^T -> t2 | r2 (each [N_PAD,256]) ----
  {
    const int nwg = (N_PAD / 128) * 4;  // 1564
    gemm_mfma<HID, 2, 2, 0><<<nwg, 256, 0, stream>>>(h1, nullptr, Wc2,
                                                     bufT, bufR, nwg);
  }
  gather_combine<HID2, 0><<<(N_NODES + 7) / 8, 256, 0, stream>>>(
      bufT, bufR, b2, offs, sorted_src, h2);

  // ---- pool + fc + log_softmax ----
  pool_final<<<NUM_GRAPHS, 256, 0, stream>>>(h2, batch, Wfc, bfc, out, N_NODES);
}

// Round 9
// 370.678 us; speedup vs baseline: 1.0512x; 1.0512x over previous
//
#include <hip/hip_runtime.h>
#include <cstdint>

#define N_NODES 50000
#define N_PAD 50176  // 196 * 256
#define N_EDGES 400000
#define IN_DIM 512
#define HID 512
#define HID2 256
#define NUM_GRAPHS 500
#define SCAN_BLOCKS 196  // ceil(50000/256)

typedef unsigned short u16;
typedef short s8v __attribute__((ext_vector_type(8)));    // 8 bf16 for MFMA A/B
typedef float f4v __attribute__((ext_vector_type(4)));    // MFMA C/D
typedef u16 u16x8 __attribute__((ext_vector_type(8)));
typedef u16 u16x4 __attribute__((ext_vector_type(4)));

__device__ __forceinline__ u16 f2bf(float f) {
  union { float f; uint32_t u; } c;
  c.f = f;
  const uint32_t u = c.u;
  return (u16)((u + 0x7fffu + ((u >> 16) & 1u)) >> 16);  // RNE
}
__device__ __forceinline__ float bf2f(u16 v) {
  union { uint32_t u; float f; } c;
  c.u = ((uint32_t)v) << 16;
  return c.f;
}

// global -> LDS async, 16B per lane. LDS dest = wave-uniform base + lane*16.
__device__ __forceinline__ void gload16(const void* g, void* l) {
  __builtin_amdgcn_global_load_lds(
      (const __attribute__((address_space(1))) void*)(uintptr_t)g,
      (__attribute__((address_space(3))) void*)(uint32_t)(uintptr_t)l, 16, 0, 0);
}

// bijective chunked XCD swizzle (m204): contiguous id-range per XCD
__device__ __forceinline__ int xcd_swizzle(int orig, int nwg) {
  const int q = nwg >> 3, rr = nwg & 7;
  const int xcd = orig & 7, idx = orig >> 3;
  return (xcd < rr ? xcd * (q + 1) : rr * (q + 1) + (xcd - rr) * q) + idx;
}

// ---------------------------------------------------------------------------
// fp32 -> bf16 flat convert (8 elems/thread)
// ---------------------------------------------------------------------------
__global__ __launch_bounds__(256) void cvt_f32_bf16(const float* __restrict__ in,
                                                    u16* __restrict__ out, int n8) {
  const int i = blockIdx.x * 256 + threadIdx.x;
  if (i >= n8) return;
  const float4 a = ((const float4*)in)[2 * i];
  const float4 b = ((const float4*)in)[2 * i + 1];
  u16x8 o;
  o[0] = f2bf(a.x); o[1] = f2bf(a.y); o[2] = f2bf(a.z); o[3] = f2bf(a.w);
  o[4] = f2bf(b.x); o[5] = f2bf(b.y); o[6] = f2bf(b.z); o[7] = f2bf(b.w);
  ((u16x8*)out)[i] = o;
}

// all 4 weight matrices in one launch
__global__ __launch_bounds__(256) void cvt_weights(const float* __restrict__ W1l,
                                                   const float* __restrict__ W1r,
                                                   const float* __restrict__ W2l,
                                                   const float* __restrict__ W2r,
                                                   u16* __restrict__ Wc1,
                                                   u16* __restrict__ Wc2) {
  const int i = blockIdx.x * 256 + threadIdx.x;
  const float* src;
  u16* dstp;
  int l;
  if (i < 32768)      { src = W1l; dstp = Wc1;          l = i; }
  else if (i < 65536) { src = W1r; dstp = Wc1 + 262144; l = i - 32768; }
  else if (i < 81920) { src = W2l; dstp = Wc2;          l = i - 65536; }
  else                { src = W2r; dstp = Wc2 + 131072; l = i - 81920; }
  const float4 a = ((const float4*)src)[2 * l];
  const float4 b = ((const float4*)src)[2 * l + 1];
  u16x8 o;
  o[0] = f2bf(a.x); o[1] = f2bf(a.y); o[2] = f2bf(a.z); o[3] = f2bf(a.w);
  o[4] = f2bf(b.x); o[5] = f2bf(b.y); o[6] = f2bf(b.z); o[7] = f2bf(b.w);
  ((u16x8*)dstp)[l] = o;
}

// ---------------------------------------------------------------------------
// 8-phase 256x256 bf16 MFMA GEMM (m201 template port).
// C[M,N] = A[M,512] * B[N,512]^T, M mult of 256. 512 thr = 8 waves (2M x 4N),
// per-wave out 128x64. BK=64, 8 K-tiles, 4 phases per K-tile:
//   phase (ks,mh): ds-read subtile (8 or 4 x b128) -> stage 1 unit (2 gloads)
//   -> counted vmcnt (phases 1:vmcnt(4), 3:vmcnt(2); never 0 mid-loop)
//   -> barrier -> lgkmcnt(0)+sched_barrier -> setprio(1) 16 MFMA setprio(0)
//   -> barrier.
// Staging of tile t+1 spread across tile t's window (1 unit/phase):
//   j0: B-k0 | j1: A-q0,A-q2 | j2: A-q1,A-q3 | j3: B-k1
// LDS 128 KB: As[2][256][64], Bs[2][2 kslices][256][32]. Conflict-free via
// pre-swizzled global source + XOR-slot reads (both-sides, rule 21):
//   A: slot = ((ks*4)|fq) ^ (fr&7);  B: slot = fq ^ ((fr>>1)&3).
// Swapped-operand MFMA -> acc holds C^T frags -> 8B packed row-major stores.
// Output n-tiles [0,NXH) -> CT, rest -> CR (both ld = LDC).
// ---------------------------------------------------------------------------
#define MFMA16(MH)                                                         \
  do {                                                                     \
    __builtin_amdgcn_s_setprio(1);                                         \
    _Pragma("unroll") for (int m4 = 0; m4 < 4; ++m4) {                     \
      _Pragma("unroll") for (int n = 0; n < 4; ++n)                        \
          acc[(MH)*4 + m4][n] = __builtin_amdgcn_mfma_f32_16x16x32_bf16(   \
              bf[n], af[m4], acc[(MH)*4 + m4][n], 0, 0, 0);                \
    }                                                                      \
    __builtin_amdgcn_s_setprio(0);                                         \
  } while (0)

#define STAGE_A(B2, TT, Q) \
  gload16(gA + (Q)*64*512 + (TT)*64, &As[B2][(Q)*4096 + ldst])
#define STAGE_B(B2, TT, KS)                                              \
  do {                                                                   \
    gload16(gB + (TT)*64 + (KS)*32, &Bs[B2][(KS)*8192 + ldst]);          \
    gload16(gB + 128*512 + (TT)*64 + (KS)*32,                            \
            &Bs[B2][(KS)*8192 + 4096 + ldst]);                           \
  } while (0)

#define LOAD_AF(B_, KS, MH)                                              \
  do {                                                                   \
    const u16* AsQ = &As[B_][(wm*2 + (MH))*4096 + fr*64 +                \
                            (((((KS) << 2) | fq) ^ frk7) * 8)];          \
    af[0] = *(const s8v*)(AsQ);                                          \
    af[1] = *(const s8v*)(AsQ + 1024);                                   \
    af[2] = *(const s8v*)(AsQ + 2048);                                   \
    af[3] = *(const s8v*)(AsQ + 3072);                                   \
  } while (0)

#define LOAD_BF(B_, KS)                                                  \
  do {                                                                   \
    const u16* BsS = &Bs[B_][(KS)*8192 + (wn*64 + fr)*32 + bslot];       \
    bf[0] = *(const s8v*)(BsS);                                          \
    bf[1] = *(const s8v*)(BsS + 512);                                    \
    bf[2] = *(const s8v*)(BsS + 1024);                                   \
    bf[3] = *(const s8v*)(BsS + 1536);                                   \
  } while (0)

template <int NXBITS, int NXH, int LDC>
__global__ __launch_bounds__(512) void gemm8p(const u16* __restrict__ A,
                                              const u16* __restrict__ B,
                                              u16* __restrict__ CT,
                                              u16* __restrict__ CR,
                                              int nwg) {
  __shared__ __align__(16) u16 As[2][256 * 64];
  __shared__ __align__(16) u16 Bs[2][2 * 256 * 32];
  const int id = xcd_swizzle(blockIdx.x, nwg);
  const int bx = id & ((1 << NXBITS) - 1);
  const int by = id >> NXBITS;
  const size_t bm = (size_t)by * 256;
  const size_t bn = (size_t)bx * 256;
  const int tid = threadIdx.x;
  const int lane = tid & 63;
  const int wv = tid >> 6;
  const int wm = wv >> 2;   // 0..1 : 128-row block
  const int wn = wv & 3;    // 0..3 : 64-col block
  const int fr = lane & 15;
  const int fq = lane >> 4;
  const int frk7 = fr & 7;
  const int bslot = (fq ^ ((fr >> 1) & 3)) * 8;

  // staging precompute (pre-swizzled global source, linear LDS dest)
  const int rA = tid >> 3;                               // 0..63
  const u16* gA = A + (bm + rA) * 512 + ((tid & 7) ^ (rA & 7)) * 8;
  const int rB = tid >> 2;                               // 0..127
  const u16* gB = B + (bn + rB) * 512 + ((tid & 3) ^ ((rB >> 1) & 3)) * 8;
  const int ldst = tid * 8;                              // u16 units

  f4v acc[8][4];
#pragma unroll
  for (int m = 0; m < 8; ++m)
#pragma unroll
    for (int n = 0; n < 4; ++n)
      acc[m][n] = f4v{0.f, 0.f, 0.f, 0.f};

  // ---- prologue: stage tile 0 fully, drain ----
  STAGE_B(0, 0, 0);
  STAGE_A(0, 0, 0); STAGE_A(0, 0, 2);
  STAGE_A(0, 0, 1); STAGE_A(0, 0, 3);
  STAGE_B(0, 0, 1);
  asm volatile("s_waitcnt vmcnt(0)" ::: "memory");
  __builtin_amdgcn_s_barrier();

#pragma unroll 2
  for (int t = 0; t < 8; ++t) {
    const int b = t & 1, b2 = b ^ 1;
    s8v af[4], bf[4];
    // ---- phase 0: ks0, mh0 ----
    LOAD_AF(b, 0, 0);
    LOAD_BF(b, 0);
    if (t < 7) STAGE_B(b2, t + 1, 0);
    __builtin_amdgcn_s_barrier();
    asm volatile("s_waitcnt lgkmcnt(0)" ::: "memory");
    __builtin_amdgcn_sched_barrier(0);
    MFMA16(0);
    __builtin_amdgcn_s_barrier();
    // ---- phase 1: ks0, mh1 ----
    LOAD_AF(b, 0, 1);
    if (t < 7) {
      STAGE_A(b2, t + 1, 0); STAGE_A(b2, t + 1, 2);
      asm volatile("s_waitcnt vmcnt(4)" ::: "memory");  // prev B-k1 landed
    } else {
      asm volatile("s_waitcnt vmcnt(0)" ::: "memory");  // final drain
    }
    __builtin_amdgcn_s_barrier();
    asm volatile("s_waitcnt lgkmcnt(0)" ::: "memory");
    __builtin_amdgcn_sched_barrier(0);
    MFMA16(1);
    __builtin_amdgcn_s_barrier();
    // ---- phase 2: ks1, mh0 ----
    LOAD_AF(b, 1, 0);
    LOAD_BF(b, 1);
    if (t < 7) { STAGE_A(b2, t + 1, 1); STAGE_A(b2, t + 1, 3); }
    __builtin_amdgcn_s_barrier();
    asm volatile("s_waitcnt lgkmcnt(0)" ::: "memory");
    __builtin_amdgcn_sched_barrier(0);
    MFMA16(0);
    __builtin_amdgcn_s_barrier();
    // ---- phase 3: ks1, mh1 ----
    LOAD_AF(b, 1, 1);
    if (t < 7) {
      STAGE_B(b2, t + 1, 1);
      asm volatile("s_waitcnt vmcnt(2)" ::: "memory");  // next tile's B-k0+A-q* landed
    }
    __builtin_amdgcn_s_barrier();
    asm volatile("s_waitcnt lgkmcnt(0)" ::: "memory");
    __builtin_amdgcn_sched_barrier(0);
    MFMA16(1);
    __builtin_amdgcn_s_barrier();
  }

  // epilogue (swapped layout): row = bm+wm*128+m*16+fr, col = n*16+fq*4+i
  u16* Cb;
  size_t cn0;
  if (bx < NXH) { Cb = CT; cn0 = (size_t)bx * 256; }
  else          { Cb = CR; cn0 = (size_t)(bx - NXH) * 256; }
  cn0 += wn * 64;
#pragma unroll
  for (int m = 0; m < 8; ++m) {
    const size_t row = bm + wm * 128 + m * 16 + fr;
#pragma unroll
    for (int n = 0; n < 4; ++n) {
      const size_t col = cn0 + n * 16 + fq * 4;
      u16x4 p;
#pragma unroll
      for (int i = 0; i < 4; ++i) p[i] = f2bf(acc[m][n][i]);
      *(u16x4*)(Cb + row * LDC + col) = p;
    }
  }
}
#undef MFMA16
#undef STAGE_A
#undef STAGE_B
#undef LOAD_AF
#undef LOAD_BF

// ---------------------------------------------------------------------------
// CSR build: histogram + hierarchical scan + cursor fill
// ---------------------------------------------------------------------------
__global__ void deg_hist(const int* __restrict__ dst, int* __restrict__ degi, int nE) {
  const int e = blockIdx.x * 256 + threadIdx.x;
  if (e < nE) atomicAdd(&degi[dst[e]], 1);
}

__device__ __forceinline__ int block_scan_excl(int v, int* total_out) {
  const int lane = threadIdx.x & 63;
  const int wid = threadIdx.x >> 6;
  int s = v;
#pragma unroll
  for (int off = 1; off < 64; off <<= 1) {
    const int t = __shfl_up(s, off);
    if (lane >= off) s += t;
  }
  __shared__ int wsum[4];
  if (lane == 63) wsum[wid] = s;
  __syncthreads();
  int base = 0;
#pragma unroll
  for (int w = 0; w < 4; ++w)
    if (w < wid) base += wsum[w];
  *total_out = wsum[0] + wsum[1] + wsum[2] + wsum[3];
  return base + s - v;
}

__global__ __launch_bounds__(256) void scan_blocks(const int* __restrict__ degi,
                                                   int* __restrict__ offs,
                                                   int* __restrict__ bsum, int n) {
  const int gid = blockIdx.x * 256 + threadIdx.x;
  const int v = (gid < n) ? degi[gid] : 0;
  int total;
  const int excl = block_scan_excl(v, &total);
  if (gid < n) offs[gid] = excl;
  if (threadIdx.x == 0) bsum[blockIdx.x] = total;
}

__global__ __launch_bounds__(256) void scan_bsums(int* __restrict__ bsum, int nb) {
  const int v = (threadIdx.x < nb) ? bsum[threadIdx.x] : 0;
  int total;
  const int excl = block_scan_excl(v, &total);
  if (threadIdx.x < nb) bsum[threadIdx.x] = excl;
}

__global__ __launch_bounds__(256) void add_base(int* __restrict__ offs,
                                                const int* __restrict__ bsum,
                                                int n, int nE) {
  const int gid = blockIdx.x * 256 + threadIdx.x;
  if (gid < n) offs[gid] += bsum[blockIdx.x];
  if (gid == 0) offs[n] = nE;
}

__global__ void fill_csr(const int* __restrict__ src, const int* __restrict__ dst,
                         const int* __restrict__ offs, int* __restrict__ cursor,
                         int* __restrict__ sorted_src, int nE) {
  const int e = blockIdx.x * 256 + threadIdx.x;
  if (e < nE) {
    const int d = dst[e];
    const int pos = offs[d] + atomicAdd(&cursor[d], 1);
    sorted_src[pos] = src[e];
  }
}

// ---------------------------------------------------------------------------
// h[n] = relu( mean_{e in CSR(n)} t[src_e] + bias + r[n] ), bf16 in, compact
// ld = D. D/8 lanes per node; 8-deep independent-load batches (avg deg = 8).
// ---------------------------------------------------------------------------
template <int D, int OUTF32>
__global__ __launch_bounds__(256) void gather_combine(
    const u16* __restrict__ t, const u16* __restrict__ r,
    const float* __restrict__ bias, const int* __restrict__ offs,
    const int* __restrict__ ssrc, void* __restrict__ hout) {
  constexpr int LPN = D / 8;
  const int node = (int)((blockIdx.x * 256u + threadIdx.x) / LPN);
  if (node >= N_NODES) return;
  const int o = (int)(threadIdx.x % LPN) * 8;
  const int beg = offs[node], end = offs[node + 1];
  float a[8] = {0.f, 0.f, 0.f, 0.f, 0.f, 0.f, 0.f, 0.f};
  int e = beg;
  for (; e + 7 < end; e += 8) {
    u16x8 v[8];
#pragma unroll
    for (int q = 0; q < 8; ++q)
      v[q] = *(const u16x8*)(t + (size_t)ssrc[e + q] * D + o);
#pragma unroll
    for (int j = 0; j < 8; ++j)
      a[j] += ((bf2f(v[0][j]) + bf2f(v[1][j])) + (bf2f(v[2][j]) + bf2f(v[3][j]))) +
              ((bf2f(v[4][j]) + bf2f(v[5][j])) + (bf2f(v[6][j]) + bf2f(v[7][j])));
  }
  if (e + 3 < end) {
    u16x8 v[4];
#pragma unroll
    for (int q = 0; q < 4; ++q)
      v[q] = *(const u16x8*)(t + (size_t)ssrc[e + q] * D + o);
#pragma unroll
    for (int j = 0; j < 8; ++j)
      a[j] += (bf2f(v[0][j]) + bf2f(v[1][j])) + (bf2f(v[2][j]) + bf2f(v[3][j]));
    e += 4;
  }
  for (; e < end; ++e) {
    const u16x8 v0 = *(const u16x8*)(t + (size_t)ssrc[e] * D + o);
#pragma unroll
    for (int j = 0; j < 8; ++j) a[j] += bf2f(v0[j]);
  }
  const float invd = 1.0f / fmaxf((float)(end - beg), 1.0f);
  const u16x8 rv = *(const u16x8*)(r + (size_t)node * D + o);
  float hv[8];
#pragma unroll
  for (int j = 0; j < 8; ++j)
    hv[j] = fmaxf(fmaf(a[j], invd, bias[o + j] + bf2f(rv[j])), 0.f);
  if (OUTF32) {
    float* hp = (float*)hout + (size_t)node * D + o;
    *(float4*)hp = make_float4(hv[0], hv[1], hv[2], hv[3]);
    *(float4*)(hp + 4) = make_float4(hv[4], hv[5], hv[6], hv[7]);
  } else {
    u16x8 ov;
#pragma unroll
    for (int j = 0; j < 8; ++j) ov[j] = f2bf(hv[j]);
    *(u16x8*)((u16*)hout + (size_t)node * D + o) = ov;
  }
}

// ---------------------------------------------------------------------------
// Fused pool + FC + log_softmax (batch sorted -> contiguous node ranges)
// h is bf16 [N_NODES, HID2]
// ---------------------------------------------------------------------------
__global__ __launch_bounds__(256) void pool_final(const u16* __restrict__ h,
                                                  const int* __restrict__ batch,
                                                  const float* __restrict__ Wfc,
                                                  const float* __restrict__ bfc,
                                                  float* __restrict__ out, int nNodes) {
  const int g = blockIdx.x;
  __shared__ int sbeg, send;
  if (threadIdx.x == 0) {
    int lo = 0, hi = nNodes;
    while (lo < hi) { const int mid = (lo + hi) >> 1; if (batch[mid] < g) lo = mid + 1; else hi = mid; }
    sbeg = lo;
    hi = nNodes;
    while (lo < hi) { const int mid = (lo + hi) >> 1; if (batch[mid] < g + 1) lo = mid + 1; else hi = mid; }
    send = lo;
  }
  __syncthreads();
  const int t = threadIdx.x;
  float s = 0.f;
  for (int row = sbeg; row < send; ++row) s += bf2f(h[(size_t)row * HID2 + t]);
  const float cnt = fmaxf((float)(send - sbeg), 1.0f);
  const float p = s / cnt;
  float d0 = p * Wfc[t];
  float d1 = p * Wfc[HID2 + t];
#pragma unroll
  for (int off = 32; off > 0; off >>= 1) {
    d0 += __shfl_down(d0, off);
    d1 += __shfl_down(d1, off);
  }
  __shared__ float r0[4], r1[4];
  const int wid = t >> 6, lane = t & 63;
  if (lane == 0) { r0[wid] = d0; r1[wid] = d1; }
  __syncthreads();
  if (t == 0) {
    const float l0 = r0[0] + r0[1] + r0[2] + r0[3] + bfc[0];
    const float l1 = r1[0] + r1[1] + r1[2] + r1[3] + bfc[1];
    const float m = fmaxf(l0, l1);
    const float lse = m + logf(expf(l0 - m) + expf(l1 - m));
    out[g * 2 + 0] = l0 - lse;
    out[g * 2 + 1] = l1 - lse;
  }
}

extern "C" void kernel_launch(void* const* d_in, const int* in_sizes, int n_in,
                              void* d_out, int out_size, void* d_ws, size_t ws_size,
                              hipStream_t stream) {
  (void)in_sizes; (void)n_in; (void)out_size; (void)ws_size;
  const float* x   = (const float*)d_in[0];
  const int* eidx  = (const int*)d_in[1];
  const int* batch = (const int*)d_in[2];
  const float* W1l = (const float*)d_in[3];
  const float* b1  = (const float*)d_in[4];
  const float* W1r = (const float*)d_in[5];
  const float* W2l = (const float*)d_in[6];
  const float* b2  = (const float*)d_in[7];
  const float* W2r = (const float*)d_in[8];
  const float* Wfc = (const float*)d_in[9];
  const float* bfc = (const float*)d_in[10];
  float* out = (float*)d_out;
  const int* src = eidx;
  const int* dst = eidx + N_EDGES;

  char* ws = (char*)d_ws;
  size_t off = 0;
  auto alloc = [&](size_t bytes) {
    char* p = ws + off;
    off += (bytes + 255) & ~(size_t)255;
    return p;
  };
  u16* bufT = (u16*)alloc((size_t)N_PAD * 512 * 2);  // t1; reused as t2 (ld 256)
  u16* bufR = (u16*)alloc((size_t)N_PAD * 512 * 2);  // r1; reused as r2 (ld 256)
  u16* bufX = (u16*)alloc((size_t)N_PAD * 512 * 2);  // x bf16
  u16* h1   = (u16*)alloc((size_t)N_PAD * 512 * 2);
  u16* h2   = (u16*)alloc((size_t)N_NODES * 256 * 2);
  u16* Wc1  = (u16*)alloc((size_t)1024 * 512 * 2);
  u16* Wc2  = (u16*)alloc((size_t)512 * 512 * 2);
  int* degi   = (int*)alloc((size_t)N_NODES * 4);    // 200192 B reserved
  int* cursor = (int*)alloc((size_t)N_NODES * 4);    // adjacent to degi
  int* offs       = (int*)alloc((size_t)(N_NODES + 1) * 4);
  int* sorted_src = (int*)alloc((size_t)N_EDGES * 4);
  int* bsum       = (int*)alloc((size_t)SCAN_BLOCKS * 4);

  // ---- CSR build ----
  hipMemsetAsync(degi, 0, 200192 + (size_t)N_NODES * 4, stream);
  deg_hist<<<(N_EDGES + 255) / 256, 256, 0, stream>>>(dst, degi, N_EDGES);
  scan_blocks<<<SCAN_BLOCKS, 256, 0, stream>>>(degi, offs, bsum, N_NODES);
  scan_bsums<<<1, 256, 0, stream>>>(bsum, SCAN_BLOCKS);
  add_base<<<SCAN_BLOCKS, 256, 0, stream>>>(offs, bsum, N_NODES, N_EDGES);
  fill_csr<<<(N_EDGES + 255) / 256, 256, 0, stream>>>(src, dst, offs, cursor,
                                                      sorted_src, N_EDGES);

  // ---- bf16 conversions ----
  cvt_f32_bf16<<<(N_NODES * (IN_DIM / 8) + 255) / 256, 256, 0, stream>>>(
      x, bufX, N_NODES * (IN_DIM / 8));
  cvt_weights<<<384, 256, 0, stream>>>(W1l, W1r, W2l, W2r, Wc1, Wc2);

  // ---- layer 1: [N_PAD,512] x [1024,512]^T -> t1 | r1 (each [N_PAD,512]) ----
  {
    const int nwg = (N_PAD / 256) * 4;  // 784 = 8*98
    gemm8p<2, 2, 512><<<nwg, 512, 0, stream>>>(bufX, Wc1, bufT, bufR, nwg);
  }
  gather_combine<HID, 0><<<(N_NODES + 3) / 4, 256, 0, stream>>>(
      bufT, bufR, b1, offs, sorted_src, h1);

  // ---- layer 2: [N_PAD,512] x [512,512]^T -> t2 | r2 (each [N_PAD,256]) ----
  {
    const int nwg = (N_PAD / 256) * 2;  // 392 = 8*49
    gemm8p<1, 1, 256><<<nwg, 512, 0, stream>>>(h1, Wc2, bufT, bufR, nwg);
  }
  gather_combine<HID2, 0><<<(N_NODES + 7) / 8, 256, 0, stream>>>(
      bufT, bufR, b2, offs, sorted_src, h2);

  // ---- pool + fc + log_softmax ----
  pool_final<<<NUM_GRAPHS, 256, 0, stream>>>(h2, batch, Wfc, bfc, out, N_NODES);
}

// Round 10
// 357.539 us; speedup vs baseline: 1.0898x; 1.0367x over previous
//
#include <hip/hip_runtime.h>
#include <cstdint>

#define N_NODES 50000
#define N_PAD 50048  // 391 * 128
#define N_EDGES 400000
#define IN_DIM 512
#define HID 512
#define HID2 256
#define NUM_GRAPHS 500
#define SCAN_BLOCKS 196  // ceil(50000/256)

typedef unsigned short u16;
typedef short s8v __attribute__((ext_vector_type(8)));    // 8 bf16 for MFMA A/B
typedef float f4v __attribute__((ext_vector_type(4)));    // MFMA C/D
typedef u16 u16x8 __attribute__((ext_vector_type(8)));
typedef u16 u16x4 __attribute__((ext_vector_type(4)));

__device__ __forceinline__ u16 f2bf(float f) {
  union { float f; uint32_t u; } c;
  c.f = f;
  const uint32_t u = c.u;
  return (u16)((u + 0x7fffu + ((u >> 16) & 1u)) >> 16);  // RNE
}
__device__ __forceinline__ float bf2f(u16 v) {
  union { uint32_t u; float f; } c;
  c.u = ((uint32_t)v) << 16;
  return c.f;
}
// packed f32x2 -> bf16x2 (RNE), gfx950 VOP3 (T12 recipe)
__device__ __forceinline__ uint32_t cvtpk(float lo, float hi) {
  uint32_t r;
  asm("v_cvt_pk_bf16_f32 %0, %1, %2" : "=v"(r) : "v"(lo), "v"(hi));
  return r;
}

// global -> LDS async, 16B per lane. LDS dest = wave-uniform base + lane*16.
__device__ __forceinline__ void gload16(const void* g, void* l) {
  __builtin_amdgcn_global_load_lds(
      (const __attribute__((address_space(1))) void*)(uintptr_t)g,
      (__attribute__((address_space(3))) void*)(uint32_t)(uintptr_t)l, 16, 0, 0);
}

// bijective chunked XCD swizzle (m204): contiguous id-range per XCD
__device__ __forceinline__ int xcd_swizzle(int orig, int nwg) {
  const int q = nwg >> 3, rr = nwg & 7;
  const int xcd = orig & 7, idx = orig >> 3;
  return (xcd < rr ? xcd * (q + 1) : rr * (q + 1) + (xcd - rr) * q) + idx;
}

// ---------------------------------------------------------------------------
// weight fp32 -> bf16 (x conversion now fused into gemm_mfma<AF32=1> staging)
// ---------------------------------------------------------------------------
__global__ __launch_bounds__(256) void cvt_weights(const float* __restrict__ W1l,
                                                   const float* __restrict__ W1r,
                                                   const float* __restrict__ W2l,
                                                   const float* __restrict__ W2r,
                                                   u16* __restrict__ Wc1,
                                                   u16* __restrict__ Wc2) {
  const int i = blockIdx.x * 256 + threadIdx.x;
  const float* src;
  u16* dstp;
  int l;
  if (i < 32768)      { src = W1l; dstp = Wc1;          l = i; }
  else if (i < 65536) { src = W1r; dstp = Wc1 + 262144; l = i - 32768; }
  else if (i < 81920) { src = W2l; dstp = Wc2;          l = i - 65536; }
  else                { src = W2r; dstp = Wc2 + 131072; l = i - 81920; }
  const float4 a = ((const float4*)src)[2 * l];
  const float4 b = ((const float4*)src)[2 * l + 1];
  u16x8 o;
  o[0] = f2bf(a.x); o[1] = f2bf(a.y); o[2] = f2bf(a.z); o[3] = f2bf(a.w);
  o[4] = f2bf(b.x); o[5] = f2bf(b.y); o[6] = f2bf(b.z); o[7] = f2bf(b.w);
  ((u16x8*)dstp)[l] = o;
}

// ---------------------------------------------------------------------------
// bf16 MFMA GEMM (R7-proven 2-phase structure): [N_PAD,K] x [NX*128,K]^T.
// 1D grid, N-fast + XCD chunk swizzle; output split CT|CR (ld = NXH*128).
// 128x128 tile, BK=32, 256 thr (4 waves 2x2), 4x4 frags of 16x16x32,
// 2-deep counted-vmcnt pipeline, both-sides LDS chunk swizzle (0 conflicts).
// AF32=1: A staged DIRECTLY from fp32 via global_load_lds into an fp32 LDS
// tile (async pipeline preserved — unlike R8's reg-staging); fragments read
// as 2x float4 and packed with v_cvt_pk_bf16_f32 (RNE, matches cvt kernel).
// Forced-linear gload dest => row=tid>>3, slot=tid&7; source chunk
// (tid&7)^((tid>>3)&7); read slots (2fq+j)^(fr&7). Involution both sides.
// Swapped-operand MFMA -> acc holds C^T frags -> 8B packed row-major stores.
// ---------------------------------------------------------------------------
template <int K, int NXL2, int NXH, int AF32>
__global__ __launch_bounds__(256) void gemm_mfma(const u16* __restrict__ A,
                                                 const float* __restrict__ Af,
                                                 const u16* __restrict__ B,
                                                 u16* __restrict__ CT,
                                                 u16* __restrict__ CR,
                                                 int nwg) {
  constexpr int ABYTES = AF32 ? 2 * 128 * 32 * 4 : 2 * 128 * 32 * 2;
  __shared__ __align__(16) char AsRaw[ABYTES];
  __shared__ __align__(16) u16 Bs[2][128 * 32];
  const int id = xcd_swizzle(blockIdx.x, nwg);
  const int bx = id & ((1 << NXL2) - 1);   // N tile (fast)
  const int by = id >> NXL2;               // M tile
  const int tid = threadIdx.x;
  const int lane = tid & 63;
  const int wave = tid >> 6;
  const int wr = (wave >> 1) * 64;
  const int wc = (wave & 1) * 64;
  const int fr = lane & 15;
  const int fq = lane >> 4;
  const size_t bm = (size_t)by * 128;
  const size_t bn = (size_t)bx * 128;

  // ---- B staging (bf16, as R7) ----
  const int r0 = tid >> 2;                         // 0..63
  const int cgB = ((tid & 3) ^ ((tid >> 3) & 3));  // swizzled k-chunk
  const u16* gB = B + (bn + r0) * K + cgB * 8;
  const int lofsB = r0 * 32 + (tid & 3) * 8;       // linear dest (u16)
  const size_t rstepB = (size_t)64 * K;
  constexpr int nt = K >> 5;

  // ---- A staging ----
  u16* uAs = (u16*)AsRaw;     // [2][128*32] u16   (!AF32)
  float* fAs = (float*)AsRaw; // [2][128*32] float (AF32)
  const u16* gA = nullptr;
  const float* gAf0 = nullptr, *gAf1 = nullptr, *gAf2 = nullptr, *gAf3 = nullptr;
  int lofsA = 0;
  if (AF32) {
    const int rA = tid >> 3;                       // 0..31
    const int cA = (tid & 7) ^ (rA & 7);           // source chunk (4 floats)
    int rr0 = (int)bm + rA;        rr0 = rr0 < N_NODES ? rr0 : N_NODES - 1;
    int rr1 = (int)bm + rA + 32;   rr1 = rr1 < N_NODES ? rr1 : N_NODES - 1;
    int rr2 = (int)bm + rA + 64;   rr2 = rr2 < N_NODES ? rr2 : N_NODES - 1;
    int rr3 = (int)bm + rA + 96;   rr3 = rr3 < N_NODES ? rr3 : N_NODES - 1;
    gAf0 = Af + (size_t)rr0 * K + cA * 4;
    gAf1 = Af + (size_t)rr1 * K + cA * 4;
    gAf2 = Af + (size_t)rr2 * K + cA * 4;
    gAf3 = Af + (size_t)rr3 * K + cA * 4;
    lofsA = tid * 4;                               // float units (linear dest)
  } else {
    gA = A + (bm + r0) * K + cgB * 8;
    lofsA = lofsB;                                 // u16 units
  }

  auto stage = [&](int b, int kt) {
    const int k0 = kt << 5;
    if (AF32) {
      gload16(gAf0 + k0, &fAs[b * 4096 + lofsA]);
      gload16(gAf1 + k0, &fAs[b * 4096 + 1024 + lofsA]);
      gload16(gAf2 + k0, &fAs[b * 4096 + 2048 + lofsA]);
      gload16(gAf3 + k0, &fAs[b * 4096 + 3072 + lofsA]);
    } else {
      gload16(gA + k0, &uAs[b * 4096 + lofsA]);
      gload16(gA + (size_t)64 * K + k0, &uAs[b * 4096 + 64 * 32 + lofsA]);
    }
    gload16(gB + k0, &Bs[b][lofsB]);
    gload16(gB + rstepB + k0, &Bs[b][lofsB + 64 * 32]);
  };
  constexpr int NLD = AF32 ? 6 : 4;  // gloads per stage

  f4v acc[4][4];
#pragma unroll
  for (int m = 0; m < 4; ++m)
#pragma unroll
    for (int n = 0; n < 4; ++n)
      acc[m][n] = f4v{0.f, 0.f, 0.f, 0.f};

  // read-side swizzles
  const int frk = fr & 7;                       // A-fp32 slot xor
  const int kx = (fr >> 1) & 3;                 // bf16 slot xor
  const int slot8 = (fq ^ kx) * 8;

  // prologue: tiles 0 and 1 in flight; wait for tile 0 only
  stage(0, 0);
  stage(1, 1);
  if (NLD == 6) asm volatile("s_waitcnt vmcnt(6)" ::: "memory");
  else          asm volatile("s_waitcnt vmcnt(4)" ::: "memory");
  __builtin_amdgcn_s_barrier();

  for (int t = 0; t < nt; ++t) {
    const int b = t & 1;
    s8v af[4], bf_[4];
    if (AF32) {
      const float* fA = fAs + b * 4096;
#pragma unroll
      for (int m = 0; m < 4; ++m) {
        const int row = wr + m * 16 + fr;
        const float4 a0 = *(const float4*)(fA + row * 32 + ((2 * fq) ^ frk) * 4);
        const float4 a1 = *(const float4*)(fA + row * 32 + ((2 * fq + 1) ^ frk) * 4);
        union { uint32_t w[4]; s8v v; } u;
        u.w[0] = cvtpk(a0.x, a0.y); u.w[1] = cvtpk(a0.z, a0.w);
        u.w[2] = cvtpk(a1.x, a1.y); u.w[3] = cvtpk(a1.z, a1.w);
        af[m] = u.v;
      }
    } else {
      const u16* curA = uAs + b * 4096;
#pragma unroll
      for (int m = 0; m < 4; ++m)
        af[m] = *(const s8v*)(curA + (wr + m * 16 + fr) * 32 + slot8);
    }
    const u16* curB = Bs[b];
#pragma unroll
    for (int n = 0; n < 4; ++n)
      bf_[n] = *(const s8v*)(curB + (wc + n * 16 + fr) * 32 + slot8);
#pragma unroll
    for (int m = 0; m < 4; ++m)
#pragma unroll
      for (int n = 0; n < 4; ++n)
        acc[m][n] = __builtin_amdgcn_mfma_f32_16x16x32_bf16(bf_[n], af[m],
                                                            acc[m][n], 0, 0, 0);
    if (t == nt - 1) break;
    __builtin_amdgcn_s_barrier();  // all waves done reading buf[t&1]
    if (t + 2 < nt) {
      stage(b, t + 2);             // refill freed buffer
      if (NLD == 6) asm volatile("s_waitcnt vmcnt(6)" ::: "memory");
      else          asm volatile("s_waitcnt vmcnt(4)" ::: "memory");
    } else {
      asm volatile("s_waitcnt vmcnt(0)" ::: "memory");
    }
    __builtin_amdgcn_s_barrier();
  }

  // epilogue (swapped layout): row = bm+wr+m*16+fr, col = cn0+n*16+fq*4+i
  u16* Cb = (bx < NXH) ? CT : CR;
  constexpr int ldc = NXH * 128;
  const size_t cn0 = (size_t)(bx - (bx >= NXH ? NXH : 0)) * 128 + wc;
#pragma unroll
  for (int m = 0; m < 4; ++m) {
    const size_t row = bm + wr + m * 16 + fr;
#pragma unroll
    for (int n = 0; n < 4; ++n) {
      const size_t col = cn0 + n * 16 + fq * 4;
      u16x4 p;
#pragma unroll
      for (int i = 0; i < 4; ++i) p[i] = f2bf(acc[m][n][i]);
      *(u16x4*)(Cb + row * ldc + col) = p;
    }
  }
}

// ---------------------------------------------------------------------------
// CSR build: histogram + hierarchical scan + cursor fill
// ---------------------------------------------------------------------------
__global__ void deg_hist(const int* __restrict__ dst, int* __restrict__ degi, int nE) {
  const int e = blockIdx.x * 256 + threadIdx.x;
  if (e < nE) atomicAdd(&degi[dst[e]], 1);
}

__device__ __forceinline__ int block_scan_excl(int v, int* total_out) {
  const int lane = threadIdx.x & 63;
  const int wid = threadIdx.x >> 6;
  int s = v;
#pragma unroll
  for (int off = 1; off < 64; off <<= 1) {
    const int t = __shfl_up(s, off);
    if (lane >= off) s += t;
  }
  __shared__ int wsum[4];
  if (lane == 63) wsum[wid] = s;
  __syncthreads();
  int base = 0;
#pragma unroll
  for (int w = 0; w < 4; ++w)
    if (w < wid) base += wsum[w];
  *total_out = wsum[0] + wsum[1] + wsum[2] + wsum[3];
  return base + s - v;
}

__global__ __launch_bounds__(256) void scan_blocks(const int* __restrict__ degi,
                                                   int* __restrict__ offs,
                                                   int* __restrict__ bsum, int n) {
  const int gid = blockIdx.x * 256 + threadIdx.x;
  const int v = (gid < n) ? degi[gid] : 0;
  int total;
  const int excl = block_scan_excl(v, &total);
  if (gid < n) offs[gid] = excl;
  if (threadIdx.x == 0) bsum[blockIdx.x] = total;
}

__global__ __launch_bounds__(256) void scan_bsums(int* __restrict__ bsum, int nb) {
  const int v = (threadIdx.x < nb) ? bsum[threadIdx.x] : 0;
  int total;
  const int excl = block_scan_excl(v, &total);
  if (threadIdx.x < nb) bsum[threadIdx.x] = excl;
}

__global__ __launch_bounds__(256) void add_base(int* __restrict__ offs,
                                                const int* __restrict__ bsum,
                                                int n, int nE) {
  const int gid = blockIdx.x * 256 + threadIdx.x;
  if (gid < n) offs[gid] += bsum[blockIdx.x];
  if (gid == 0) offs[n] = nE;
}

__global__ void fill_csr(const int* __restrict__ src, const int* __restrict__ dst,
                         const int* __restrict__ offs, int* __restrict__ cursor,
                         int* __restrict__ sorted_src, int nE) {
  const int e = blockIdx.x * 256 + threadIdx.x;
  if (e < nE) {
    const int d = dst[e];
    const int pos = offs[d] + atomicAdd(&cursor[d], 1);
    sorted_src[pos] = src[e];
  }
}

// ---------------------------------------------------------------------------
// h[n] = relu( mean_{e in CSR(n)} t[src_e] + bias + r[n] ), bf16 in, compact
// ld = D. D/8 lanes per node; 8-deep independent-load batches (avg deg = 8).
// ---------------------------------------------------------------------------
template <int D>
__global__ __launch_bounds__(256) void gather_combine(
    const u16* __restrict__ t, const u16* __restrict__ r,
    const float* __restrict__ bias, const int* __restrict__ offs,
    const int* __restrict__ ssrc, u16* __restrict__ hout) {
  constexpr int LPN = D / 8;
  const int node = (int)((blockIdx.x * 256u + threadIdx.x) / LPN);
  if (node >= N_NODES) return;
  const int o = (int)(threadIdx.x % LPN) * 8;
  const int beg = offs[node], end = offs[node + 1];
  float a[8] = {0.f, 0.f, 0.f, 0.f, 0.f, 0.f, 0.f, 0.f};
  int e = beg;
  for (; e + 7 < end; e += 8) {
    u16x8 v[8];
#pragma unroll
    for (int q = 0; q < 8; ++q)
      v[q] = *(const u16x8*)(t + (size_t)ssrc[e + q] * D + o);
#pragma unroll
    for (int j = 0; j < 8; ++j)
      a[j] += ((bf2f(v[0][j]) + bf2f(v[1][j])) + (bf2f(v[2][j]) + bf2f(v[3][j]))) +
              ((bf2f(v[4][j]) + bf2f(v[5][j])) + (bf2f(v[6][j]) + bf2f(v[7][j])));
  }
  if (e + 3 < end) {
    u16x8 v[4];
#pragma unroll
    for (int q = 0; q < 4; ++q)
      v[q] = *(const u16x8*)(t + (size_t)ssrc[e + q] * D + o);
#pragma unroll
    for (int j = 0; j < 8; ++j)
      a[j] += (bf2f(v[0][j]) + bf2f(v[1][j])) + (bf2f(v[2][j]) + bf2f(v[3][j]));
    e += 4;
  }
  for (; e < end; ++e) {
    const u16x8 v0 = *(const u16x8*)(t + (size_t)ssrc[e] * D + o);
#pragma unroll
    for (int j = 0; j < 8; ++j) a[j] += bf2f(v0[j]);
  }
  const float invd = 1.0f / fmaxf((float)(end - beg), 1.0f);
  const u16x8 rv = *(const u16x8*)(r + (size_t)node * D + o);
  u16x8 ov;
#pragma unroll
  for (int j = 0; j < 8; ++j)
    ov[j] = f2bf(fmaxf(fmaf(a[j], invd, bias[o + j] + bf2f(rv[j])), 0.f));
  *(u16x8*)(hout + (size_t)node * D + o) = ov;
}

// ---------------------------------------------------------------------------
// Fused pool + FC + log_softmax (batch sorted -> contiguous node ranges)
// h is bf16 [N_NODES, HID2]
// ---------------------------------------------------------------------------
__global__ __launch_bounds__(256) void pool_final(const u16* __restrict__ h,
                                                  const int* __restrict__ batch,
                                                  const float* __restrict__ Wfc,
                                                  const float* __restrict__ bfc,
                                                  float* __restrict__ out, int nNodes) {
  const int g = blockIdx.x;
  __shared__ int sbeg, send;
  if (threadIdx.x == 0) {
    int lo = 0, hi = nNodes;
    while (lo < hi) { const int mid = (lo + hi) >> 1; if (batch[mid] < g) lo = mid + 1; else hi = mid; }
    sbeg = lo;
    hi = nNodes;
    while (lo < hi) { const int mid = (lo + hi) >> 1; if (batch[mid] < g + 1) lo = mid + 1; else hi = mid; }
    send = lo;
  }
  __syncthreads();
  const int t = threadIdx.x;
  float s = 0.f;
  for (int row = sbeg; row < send; ++row) s += bf2f(h[(size_t)row * HID2 + t]);
  const float cnt = fmaxf((float)(send - sbeg), 1.0f);
  const float p = s / cnt;
  float d0 = p * Wfc[t];
  float d1 = p * Wfc[HID2 + t];
#pragma unroll
  for (int off = 32; off > 0; off >>= 1) {
    d0 += __shfl_down(d0, off);
    d1 += __shfl_down(d1, off);
  }
  __shared__ float r0[4], r1[4];
  const int wid = t >> 6, lane = t & 63;
  if (lane == 0) { r0[wid] = d0; r1[wid] = d1; }
  __syncthreads();
  if (t == 0) {
    const float l0 = r0[0] + r0[1] + r0[2] + r0[3] + bfc[0];
    const float l1 = r1[0] + r1[1] + r1[2] + r1[3] + bfc[1];
    const float m = fmaxf(l0, l1);
    const float lse = m + logf(expf(l0 - m) + expf(l1 - m));
    out[g * 2 + 0] = l0 - lse;
    out[g * 2 + 1] = l1 - lse;
  }
}

extern "C" void kernel_launch(void* const* d_in, const int* in_sizes, int n_in,
                              void* d_out, int out_size, void* d_ws, size_t ws_size,
                              hipStream_t stream) {
  (void)in_sizes; (void)n_in; (void)out_size; (void)ws_size;
  const float* x   = (const float*)d_in[0];
  const int* eidx  = (const int*)d_in[1];
  const int* batch = (const int*)d_in[2];
  const float* W1l = (const float*)d_in[3];
  const float* b1  = (const float*)d_in[4];
  const float* W1r = (const float*)d_in[5];
  const float* W2l = (const float*)d_in[6];
  const float* b2  = (const float*)d_in[7];
  const float* W2r = (const float*)d_in[8];
  const float* Wfc = (const float*)d_in[9];
  const float* bfc = (const float*)d_in[10];
  float* out = (float*)d_out;
  const int* src = eidx;
  const int* dst = eidx + N_EDGES;

  char* ws = (char*)d_ws;
  size_t off = 0;
  auto alloc = [&](size_t bytes) {
    char* p = ws + off;
    off += (bytes + 255) & ~(size_t)255;
    return p;
  };
  u16* bufT = (u16*)alloc((size_t)N_PAD * 512 * 2);  // t1; reused as t2 (ld 256)
  u16* bufR = (u16*)alloc((size_t)N_PAD * 512 * 2);  // r1; reused as r2 (ld 256)
  u16* h1   = (u16*)alloc((size_t)N_PAD * 512 * 2);
  u16* h2   = (u16*)alloc((size_t)N_NODES * 256 * 2);
  u16* Wc1  = (u16*)alloc((size_t)1024 * 512 * 2);
  u16* Wc2  = (u16*)alloc((size_t)512 * 512 * 2);
  int* degi   = (int*)alloc((size_t)N_NODES * 4);    // 200192 B reserved
  int* cursor = (int*)alloc((size_t)N_NODES * 4);    // adjacent to degi
  int* offs       = (int*)alloc((size_t)(N_NODES + 1) * 4);
  int* sorted_src = (int*)alloc((size_t)N_EDGES * 4);
  int* bsum       = (int*)alloc((size_t)SCAN_BLOCKS * 4);

  // ---- CSR build ----
  hipMemsetAsync(degi, 0, 200192 + (size_t)N_NODES * 4, stream);
  deg_hist<<<(N_EDGES + 255) / 256, 256, 0, stream>>>(dst, degi, N_EDGES);
  scan_blocks<<<SCAN_BLOCKS, 256, 0, stream>>>(degi, offs, bsum, N_NODES);
  scan_bsums<<<1, 256, 0, stream>>>(bsum, SCAN_BLOCKS);
  add_base<<<SCAN_BLOCKS, 256, 0, stream>>>(offs, bsum, N_NODES, N_EDGES);
  fill_csr<<<(N_EDGES + 255) / 256, 256, 0, stream>>>(src, dst, offs, cursor,
                                                      sorted_src, N_EDGES);

  // ---- weight conversions (x read directly by GEMM1) ----
  cvt_weights<<<384, 256, 0, stream>>>(W1l, W1r, W2l, W2r, Wc1, Wc2);

  // ---- layer 1: fp32 x [N_PAD,512] x [1024,512]^T -> t1 | r1 ----
  {
    const int nwg = (N_PAD / 128) * 8;  // 3128
    gemm_mfma<IN_DIM, 3, 4, 1><<<nwg, 256, 0, stream>>>(nullptr, x, Wc1,
                                                        bufT, bufR, nwg);
  }
  gather_combine<HID><<<(N_NODES + 3) / 4, 256, 0, stream>>>(
      bufT, bufR, b1, offs, sorted_src, h1);

  // ---- layer 2: [N_PAD,512] x [512,512]^T -> t2 | r2 (each [N_PAD,256]) ----
  {
    const int nwg = (N_PAD / 128) * 4;  // 1564
    gemm_mfma<HID, 2, 2, 0><<<nwg, 256, 0, stream>>>(h1, nullptr, Wc2,
                                                     bufT, bufR, nwg);
  }
  gather_combine<HID2><<<(N_NODES + 7) / 8, 256, 0, stream>>>(
      bufT, bufR, b2, offs, sorted_src, h2);

  // ---- pool + fc + log_softmax ----
  pool_final<<<NUM_GRAPHS, 256, 0, stream>>>(h2, batch, Wfc, bfc, out, N_NODES);
}

// Round 11
// 345.551 us; speedup vs baseline: 1.1276x; 1.0347x over previous
//
#include <hip/hip_runtime.h>
#include <cstdint>

#define N_NODES 50000
#define N_PAD 50048  // 391 * 128
#define N_EDGES 400000
#define IN_DIM 512
#define HID 512
#define HID2 256
#define NUM_GRAPHS 500
#define SCAN_BLOCKS 196  // ceil(50000/256)

typedef unsigned short u16;
typedef short s8v __attribute__((ext_vector_type(8)));    // 8 bf16 for MFMA A/B
typedef float f4v __attribute__((ext_vector_type(4)));    // MFMA C/D
typedef u16 u16x8 __attribute__((ext_vector_type(8)));
typedef u16 u16x4 __attribute__((ext_vector_type(4)));

__device__ __forceinline__ u16 f2bf(float f) {
  union { float f; uint32_t u; } c;
  c.f = f;
  const uint32_t u = c.u;
  return (u16)((u + 0x7fffu + ((u >> 16) & 1u)) >> 16);  // RNE
}
__device__ __forceinline__ float bf2f(u16 v) {
  union { uint32_t u; float f; } c;
  c.u = ((uint32_t)v) << 16;
  return c.f;
}

// global -> LDS async, 16B per lane. LDS dest = wave-uniform base + lane*16.
__device__ __forceinline__ void gload16(const void* g, void* l) {
  __builtin_amdgcn_global_load_lds(
      (const __attribute__((address_space(1))) void*)(uintptr_t)g,
      (__attribute__((address_space(3))) void*)(uint32_t)(uintptr_t)l, 16, 0, 0);
}

// bijective chunked XCD swizzle (m204): contiguous id-range per XCD
__device__ __forceinline__ int xcd_swizzle(int orig, int nwg) {
  const int q = nwg >> 3, rr = nwg & 7;
  const int xcd = orig & 7, idx = orig >> 3;
  return (xcd < rr ? xcd * (q + 1) : rr * (q + 1) + (xcd - rr) * q) + idx;
}

// ---------------------------------------------------------------------------
// fp32 -> bf16 flat convert (8 elems/thread)
// ---------------------------------------------------------------------------
__global__ __launch_bounds__(256) void cvt_f32_bf16(const float* __restrict__ in,
                                                    u16* __restrict__ out, int n8) {
  const int i = blockIdx.x * 256 + threadIdx.x;
  if (i >= n8) return;
  const float4 a = ((const float4*)in)[2 * i];
  const float4 b = ((const float4*)in)[2 * i + 1];
  u16x8 o;
  o[0] = f2bf(a.x); o[1] = f2bf(a.y); o[2] = f2bf(a.z); o[3] = f2bf(a.w);
  o[4] = f2bf(b.x); o[5] = f2bf(b.y); o[6] = f2bf(b.z); o[7] = f2bf(b.w);
  ((u16x8*)out)[i] = o;
}

// all 4 weight matrices in one launch
__global__ __launch_bounds__(256) void cvt_weights(const float* __restrict__ W1l,
                                                   const float* __restrict__ W1r,
                                                   const float* __restrict__ W2l,
                                                   const float* __restrict__ W2r,
                                                   u16* __restrict__ Wc1,
                                                   u16* __restrict__ Wc2) {
  const int i = blockIdx.x * 256 + threadIdx.x;
  const float* src;
  u16* dstp;
  int l;
  if (i < 32768)      { src = W1l; dstp = Wc1;          l = i; }
  else if (i < 65536) { src = W1r; dstp = Wc1 + 262144; l = i - 32768; }
  else if (i < 81920) { src = W2l; dstp = Wc2;          l = i - 65536; }
  else                { src = W2r; dstp = Wc2 + 131072; l = i - 81920; }
  const float4 a = ((const float4*)src)[2 * l];
  const float4 b = ((const float4*)src)[2 * l + 1];
  u16x8 o;
  o[0] = f2bf(a.x); o[1] = f2bf(a.y); o[2] = f2bf(a.z); o[3] = f2bf(a.w);
  o[4] = f2bf(b.x); o[5] = f2bf(b.y); o[6] = f2bf(b.z); o[7] = f2bf(b.w);
  ((u16x8*)dstp)[l] = o;
}

// ---------------------------------------------------------------------------
// bf16 MFMA GEMM (R7-proven): [N_PAD,K] x [NX*128,K]^T. 1D grid, N-fast +
// XCD chunk swizzle; output split CT|CR (ld = NXH*128).
// 128x128 tile, BK=32, 256 thr (4 waves 2x2), 4x4 frags of 16x16x32.
// 2-deep counted-vmcnt pipeline (T4); both-sides LDS chunk swizzle (T2,
// rule 21): linear gload dest, global source chunk (tid&3)^((tid>>3)&3),
// read slot fq^((fr>>1)&3) — measured 0 bank conflicts.
// Swapped-operand MFMA -> acc holds C^T frags -> 8B packed row-major stores.
// Measured: 85 us (L1) / 42 us (L2) — 2-phase structure ceiling (m233).
// ---------------------------------------------------------------------------
template <int K, int NXL2, int NXH>
__global__ __launch_bounds__(256) void gemm_mfma(const u16* __restrict__ A,
                                                 const u16* __restrict__ B,
                                                 u16* __restrict__ CT,
                                                 u16* __restrict__ CR,
                                                 int nwg) {
  __shared__ __align__(16) u16 As[2][128 * 32];
  __shared__ __align__(16) u16 Bs[2][128 * 32];
  const int id = xcd_swizzle(blockIdx.x, nwg);
  const int bx = id & ((1 << NXL2) - 1);   // N tile (fast)
  const int by = id >> NXL2;               // M tile
  const int tid = threadIdx.x;
  const int lane = tid & 63;
  const int wave = tid >> 6;
  const int wr = (wave >> 1) * 64;
  const int wc = (wave & 1) * 64;
  const int fr = lane & 15;
  const int fq = lane >> 4;
  const size_t bm = (size_t)by * 128;
  const size_t bn = (size_t)bx * 128;

  // staging: linear LDS dest; global chunk pre-swizzled
  const int r0 = tid >> 2;                              // 0..63
  const int c0 = (((tid & 3) ^ ((tid >> 3) & 3)) * 8);  // swizzled k-chunk
  const u16* gA = A + (bm + r0) * K + c0;
  const u16* gB = B + (bn + r0) * K + c0;
  const size_t rstep = (size_t)64 * K;
  const int lofs = r0 * 32 + (tid & 3) * 8;             // linear dest
  constexpr int nt = K >> 5;

  auto stage = [&](int b, int kt) {
    const int k0 = kt << 5;
    gload16(gA + k0, &As[b][lofs]);
    gload16(gA + rstep + k0, &As[b][lofs + 64 * 32]);
    gload16(gB + k0, &Bs[b][lofs]);
    gload16(gB + rstep + k0, &Bs[b][lofs + 64 * 32]);
  };

  f4v acc[4][4];
#pragma unroll
  for (int m = 0; m < 4; ++m)
#pragma unroll
    for (int n = 0; n < 4; ++n)
      acc[m][n] = f4v{0.f, 0.f, 0.f, 0.f};

  // read-side swizzle: slot = fq ^ kx, kx = (fr>>1)&3 (row-pair parity)
  const int kx = (fr >> 1) & 3;
  const int slot8 = (fq ^ kx) * 8;

  // prologue: tiles 0 and 1 in flight; wait for tile 0 only
  stage(0, 0);
  stage(1, 1);
  asm volatile("s_waitcnt vmcnt(4)" ::: "memory");
  __builtin_amdgcn_s_barrier();

  for (int t = 0; t < nt; ++t) {
    const u16* curA = As[t & 1];
    const u16* curB = Bs[t & 1];
    s8v af[4], bf_[4];
#pragma unroll
    for (int m = 0; m < 4; ++m)
      af[m] = *(const s8v*)(curA + (wr + m * 16 + fr) * 32 + slot8);
#pragma unroll
    for (int n = 0; n < 4; ++n)
      bf_[n] = *(const s8v*)(curB + (wc + n * 16 + fr) * 32 + slot8);
#pragma unroll
    for (int m = 0; m < 4; ++m)
#pragma unroll
      for (int n = 0; n < 4; ++n)
        acc[m][n] = __builtin_amdgcn_mfma_f32_16x16x32_bf16(bf_[n], af[m],
                                                            acc[m][n], 0, 0, 0);
    if (t == nt - 1) break;
    __builtin_amdgcn_s_barrier();  // all waves done ds_reading buf[t&1]
    if (t + 2 < nt) {
      stage(t & 1, t + 2);         // refill freed buffer
      asm volatile("s_waitcnt vmcnt(4)" ::: "memory");
    } else {
      asm volatile("s_waitcnt vmcnt(0)" ::: "memory");
    }
    __builtin_amdgcn_s_barrier();
  }

  // epilogue (swapped layout): row = bm+wr+m*16+fr, col = cn0+n*16+fq*4+i
  u16* Cb = (bx < NXH) ? CT : CR;
  constexpr int ldc = NXH * 128;
  const size_t cn0 = (size_t)(bx - (bx >= NXH ? NXH : 0)) * 128 + wc;
#pragma unroll
  for (int m = 0; m < 4; ++m) {
    const size_t row = bm + wr + m * 16 + fr;
#pragma unroll
    for (int n = 0; n < 4; ++n) {
      const size_t col = cn0 + n * 16 + fq * 4;
      u16x4 p;
#pragma unroll
      for (int i = 0; i < 4; ++i) p[i] = f2bf(acc[m][n][i]);
      *(u16x4*)(Cb + row * ldc + col) = p;
    }
  }
}

// ---------------------------------------------------------------------------
// CSR build: histogram + hierarchical scan + cursor fill
// ---------------------------------------------------------------------------
__global__ void deg_hist(const int* __restrict__ dst, int* __restrict__ degi, int nE) {
  const int e = blockIdx.x * 256 + threadIdx.x;
  if (e < nE) atomicAdd(&degi[dst[e]], 1);
}

__device__ __forceinline__ int block_scan_excl(int v, int* total_out) {
  const int lane = threadIdx.x & 63;
  const int wid = threadIdx.x >> 6;
  int s = v;
#pragma unroll
  for (int off = 1; off < 64; off <<= 1) {
    const int t = __shfl_up(s, off);
    if (lane >= off) s += t;
  }
  __shared__ int wsum[4];
  if (lane == 63) wsum[wid] = s;
  __syncthreads();
  int base = 0;
#pragma unroll
  for (int w = 0; w < 4; ++w)
    if (w < wid) base += wsum[w];
  *total_out = wsum[0] + wsum[1] + wsum[2] + wsum[3];
  return base + s - v;
}

__global__ __launch_bounds__(256) void scan_blocks(const int* __restrict__ degi,
                                                   int* __restrict__ offs,
                                                   int* __restrict__ bsum, int n) {
  const int gid = blockIdx.x * 256 + threadIdx.x;
  const int v = (gid < n) ? degi[gid] : 0;
  int total;
  const int excl = block_scan_excl(v, &total);
  if (gid < n) offs[gid] = excl;
  if (threadIdx.x == 0) bsum[blockIdx.x] = total;
}

__global__ __launch_bounds__(256) void scan_bsums(int* __restrict__ bsum, int nb) {
  const int v = (threadIdx.x < nb) ? bsum[threadIdx.x] : 0;
  int total;
  const int excl = block_scan_excl(v, &total);
  if (threadIdx.x < nb) bsum[threadIdx.x] = excl;
}

__global__ __launch_bounds__(256) void add_base(int* __restrict__ offs,
                                                const int* __restrict__ bsum,
                                                int n, int nE) {
  const int gid = blockIdx.x * 256 + threadIdx.x;
  if (gid < n) offs[gid] += bsum[blockIdx.x];
  if (gid == 0) offs[n] = nE;
}

__global__ void fill_csr(const int* __restrict__ src, const int* __restrict__ dst,
                         const int* __restrict__ offs, int* __restrict__ cursor,
                         int* __restrict__ sorted_src, int nE) {
  const int e = blockIdx.x * 256 + threadIdx.x;
  if (e < nE) {
    const int d = dst[e];
    const int pos = offs[d] + atomicAdd(&cursor[d], 1);
    sorted_src[pos] = src[e];
  }
}

// ---------------------------------------------------------------------------
// h[n] = relu( mean_{e in CSR(n)} t[src_e] + bias + r[n] ), bf16 in/out,
// compact ld = D. D/8 lanes per node; 8-deep independent-load batches.
// ---------------------------------------------------------------------------
template <int D>
__global__ __launch_bounds__(256) void gather_combine(
    const u16* __restrict__ t, const u16* __restrict__ r,
    const float* __restrict__ bias, const int* __restrict__ offs,
    const int* __restrict__ ssrc, u16* __restrict__ hout) {
  constexpr int LPN = D / 8;
  const int node = (int)((blockIdx.x * 256u + threadIdx.x) / LPN);
  if (node >= N_NODES) return;
  const int o = (int)(threadIdx.x % LPN) * 8;
  const int beg = offs[node], end = offs[node + 1];
  float a[8] = {0.f, 0.f, 0.f, 0.f, 0.f, 0.f, 0.f, 0.f};
  int e = beg;
  for (; e + 7 < end; e += 8) {
    u16x8 v[8];
#pragma unroll
    for (int q = 0; q < 8; ++q)
      v[q] = *(const u16x8*)(t + (size_t)ssrc[e + q] * D + o);
#pragma unroll
    for (int j = 0; j < 8; ++j)
      a[j] += ((bf2f(v[0][j]) + bf2f(v[1][j])) + (bf2f(v[2][j]) + bf2f(v[3][j]))) +
              ((bf2f(v[4][j]) + bf2f(v[5][j])) + (bf2f(v[6][j]) + bf2f(v[7][j])));
  }
  if (e + 3 < end) {
    u16x8 v[4];
#pragma unroll
    for (int q = 0; q < 4; ++q)
      v[q] = *(const u16x8*)(t + (size_t)ssrc[e + q] * D + o);
#pragma unroll
    for (int j = 0; j < 8; ++j)
      a[j] += (bf2f(v[0][j]) + bf2f(v[1][j])) + (bf2f(v[2][j]) + bf2f(v[3][j]));
    e += 4;
  }
  for (; e < end; ++e) {
    const u16x8 v0 = *(const u16x8*)(t + (size_t)ssrc[e] * D + o);
#pragma unroll
    for (int j = 0; j < 8; ++j) a[j] += bf2f(v0[j]);
  }
  const float invd = 1.0f / fmaxf((float)(end - beg), 1.0f);
  const u16x8 rv = *(const u16x8*)(r + (size_t)node * D + o);
  u16x8 ov;
#pragma unroll
  for (int j = 0; j < 8; ++j)
    ov[j] = f2bf(fmaxf(fmaf(a[j], invd, bias[o + j] + bf2f(rv[j])), 0.f));
  *(u16x8*)(hout + (size_t)node * D + o) = ov;
}

// ---------------------------------------------------------------------------
// Fused pool + FC + log_softmax (batch sorted -> contiguous node ranges)
// h is bf16 [N_NODES, HID2]
// ---------------------------------------------------------------------------
__global__ __launch_bounds__(256) void pool_final(const u16* __restrict__ h,
                                                  const int* __restrict__ batch,
                                                  const float* __restrict__ Wfc,
                                                  const float* __restrict__ bfc,
                                                  float* __restrict__ out, int nNodes) {
  const int g = blockIdx.x;
  __shared__ int sbeg, send;
  if (threadIdx.x == 0) {
    int lo = 0, hi = nNodes;
    while (lo < hi) { const int mid = (lo + hi) >> 1; if (batch[mid] < g) lo = mid + 1; else hi = mid; }
    sbeg = lo;
    hi = nNodes;
    while (lo < hi) { const int mid = (lo + hi) >> 1; if (batch[mid] < g + 1) lo = mid + 1; else hi = mid; }
    send = lo;
  }
  __syncthreads();
  const int t = threadIdx.x;
  float s = 0.f;
  for (int row = sbeg; row < send; ++row) s += bf2f(h[(size_t)row * HID2 + t]);
  const float cnt = fmaxf((float)(send - sbeg), 1.0f);
  const float p = s / cnt;
  float d0 = p * Wfc[t];
  float d1 = p * Wfc[HID2 + t];
#pragma unroll
  for (int off = 32; off > 0; off >>= 1) {
    d0 += __shfl_down(d0, off);
    d1 += __shfl_down(d1, off);
  }
  __shared__ float r0[4], r1[4];
  const int wid = t >> 6, lane = t & 63;
  if (lane == 0) { r0[wid] = d0; r1[wid] = d1; }
  __syncthreads();
  if (t == 0) {
    const float l0 = r0[0] + r0[1] + r0[2] + r0[3] + bfc[0];
    const float l1 = r1[0] + r1[1] + r1[2] + r1[3] + bfc[1];
    const float m = fmaxf(l0, l1);
    const float lse = m + logf(expf(l0 - m) + expf(l1 - m));
    out[g * 2 + 0] = l0 - lse;
    out[g * 2 + 1] = l1 - lse;
  }
}

extern "C" void kernel_launch(void* const* d_in, const int* in_sizes, int n_in,
                              void* d_out, int out_size, void* d_ws, size_t ws_size,
                              hipStream_t stream) {
  (void)in_sizes; (void)n_in; (void)out_size; (void)ws_size;
  const float* x   = (const float*)d_in[0];
  const int* eidx  = (const int*)d_in[1];
  const int* batch = (const int*)d_in[2];
  const float* W1l = (const float*)d_in[3];
  const float* b1  = (const float*)d_in[4];
  const float* W1r = (const float*)d_in[5];
  const float* W2l = (const float*)d_in[6];
  const float* b2  = (const float*)d_in[7];
  const float* W2r = (const float*)d_in[8];
  const float* Wfc = (const float*)d_in[9];
  const float* bfc = (const float*)d_in[10];
  float* out = (float*)d_out;
  const int* src = eidx;
  const int* dst = eidx + N_EDGES;

  char* ws = (char*)d_ws;
  size_t off = 0;
  auto alloc = [&](size_t bytes) {
    char* p = ws + off;
    off += (bytes + 255) & ~(size_t)255;
    return p;
  };
  u16* bufT = (u16*)alloc((size_t)N_PAD * 512 * 2);  // t1; reused as t2 (ld 256)
  u16* bufR = (u16*)alloc((size_t)N_PAD * 512 * 2);  // r1; reused as r2 (ld 256)
  u16* bufX = (u16*)alloc((size_t)N_PAD * 512 * 2);  // x bf16
  u16* h1   = (u16*)alloc((size_t)N_PAD * 512 * 2);
  u16* h2   = (u16*)alloc((size_t)N_NODES * 256 * 2);
  u16* Wc1  = (u16*)alloc((size_t)1024 * 512 * 2);
  u16* Wc2  = (u16*)alloc((size_t)512 * 512 * 2);
  int* degi   = (int*)alloc((size_t)N_NODES * 4);    // 200192 B reserved
  int* cursor = (int*)alloc((size_t)N_NODES * 4);    // adjacent to degi
  int* offs       = (int*)alloc((size_t)(N_NODES + 1) * 4);
  int* sorted_src = (int*)alloc((size_t)N_EDGES * 4);
  int* bsum       = (int*)alloc((size_t)SCAN_BLOCKS * 4);

  // ---- CSR build ----
  hipMemsetAsync(degi, 0, 200192 + (size_t)N_NODES * 4, stream);
  deg_hist<<<(N_EDGES + 255) / 256, 256, 0, stream>>>(dst, degi, N_EDGES);
  scan_blocks<<<SCAN_BLOCKS, 256, 0, stream>>>(degi, offs, bsum, N_NODES);
  scan_bsums<<<1, 256, 0, stream>>>(bsum, SCAN_BLOCKS);
  add_base<<<SCAN_BLOCKS, 256, 0, stream>>>(offs, bsum, N_NODES, N_EDGES);
  fill_csr<<<(N_EDGES + 255) / 256, 256, 0, stream>>>(src, dst, offs, cursor,
                                                      sorted_src, N_EDGES);

  // ---- bf16 conversions ----
  cvt_f32_bf16<<<(N_NODES * (IN_DIM / 8) + 255) / 256, 256, 0, stream>>>(
      x, bufX, N_NODES * (IN_DIM / 8));
  cvt_weights<<<384, 256, 0, stream>>>(W1l, W1r, W2l, W2r, Wc1, Wc2);

  // ---- layer 1: [N_PAD,512] x [1024,512]^T -> t1 | r1 (each [N_PAD,512]) ----
  {
    const int nwg = (N_PAD / 128) * 8;  // 3128
    gemm_mfma<IN_DIM, 3, 4><<<nwg, 256, 0, stream>>>(bufX, Wc1, bufT, bufR, nwg);
  }
  gather_combine<HID><<<(N_NODES + 3) / 4, 256, 0, stream>>>(
      bufT, bufR, b1, offs, sorted_src, h1);

  // ---- layer 2: [N_PAD,512] x [512,512]^T -> t2 | r2 (each [N_PAD,256]) ----
  {
    const int nwg = (N_PAD / 128) * 4;  // 1564
    gemm_mfma<HID, 2, 2><<<nwg, 256, 0, stream>>>(h1, Wc2, bufT, bufR, nwg);
  }
  gather_combine<HID2><<<(N_NODES + 7) / 8, 256, 0, stream>>>(
      bufT, bufR, b2, offs, sorted_src, h2);

  // ---- pool + fc + log_softmax ----
  pool_final<<<NUM_GRAPHS, 256, 0, stream>>>(h2, batch, Wfc, bfc, out, N_NODES);
}

// Round 12
// 340.460 us; speedup vs baseline: 1.1445x; 1.0150x over previous
//
#include <hip/hip_runtime.h>
#include <cstdint>

#define N_NODES 50000
#define N_PAD 50048  // 391 * 128
#define N_EDGES 400000
#define IN_DIM 512
#define HID 512
#define HID2 256
#define NUM_GRAPHS 500
#define SCAN_BLOCKS 196  // ceil(50000/256)

typedef unsigned short u16;
typedef short s8v __attribute__((ext_vector_type(8)));    // 8 bf16 for MFMA A/B
typedef float f4v __attribute__((ext_vector_type(4)));    // MFMA C/D
typedef u16 u16x8 __attribute__((ext_vector_type(8)));
typedef u16 u16x4 __attribute__((ext_vector_type(4)));

__device__ __forceinline__ u16 f2bf(float f) {
  union { float f; uint32_t u; } c;
  c.f = f;
  const uint32_t u = c.u;
  return (u16)((u + 0x7fffu + ((u >> 16) & 1u)) >> 16);  // RNE
}
__device__ __forceinline__ float bf2f(u16 v) {
  union { uint32_t u; float f; } c;
  c.u = ((uint32_t)v) << 16;
  return c.f;
}

// global -> LDS async, 16B per lane. LDS dest = wave-uniform base + lane*16.
__device__ __forceinline__ void gload16(const void* g, void* l) {
  __builtin_amdgcn_global_load_lds(
      (const __attribute__((address_space(1))) void*)(uintptr_t)g,
      (__attribute__((address_space(3))) void*)(uint32_t)(uintptr_t)l, 16, 0, 0);
}

// bijective chunked XCD swizzle (m204): contiguous id-range per XCD
__device__ __forceinline__ int xcd_swizzle(int orig, int nwg) {
  const int q = nwg >> 3, rr = nwg & 7;
  const int xcd = orig & 7, idx = orig >> 3;
  return (xcd < rr ? xcd * (q + 1) : rr * (q + 1) + (xcd - rr) * q) + idx;
}

// ---------------------------------------------------------------------------
// Merged prep: cvt_x (blocks 0..12499) + cvt_weights (12500..12883) +
// deg_hist (12884..14446). All three are independent; merging saves 2
// launches and overlaps atomic latency with BW streaming.
// ---------------------------------------------------------------------------
__global__ __launch_bounds__(256) void prep_kernel(
    const float* __restrict__ x, u16* __restrict__ bufX,
    const float* __restrict__ W1l, const float* __restrict__ W1r,
    const float* __restrict__ W2l, const float* __restrict__ W2r,
    u16* __restrict__ Wc1, u16* __restrict__ Wc2,
    const int* __restrict__ dst, int* __restrict__ degi) {
  const int b = blockIdx.x;
  if (b < 12500) {
    // x fp32 -> bf16, 8 elems/thread; n8 = 3.2e6 exactly covers 12500 blocks
    const int i = b * 256 + threadIdx.x;
    const float4 a = ((const float4*)x)[2 * i];
    const float4 c = ((const float4*)x)[2 * i + 1];
    u16x8 o;
    o[0] = f2bf(a.x); o[1] = f2bf(a.y); o[2] = f2bf(a.z); o[3] = f2bf(a.w);
    o[4] = f2bf(c.x); o[5] = f2bf(c.y); o[6] = f2bf(c.z); o[7] = f2bf(c.w);
    ((u16x8*)bufX)[i] = o;
  } else if (b < 12884) {
    const int i = (b - 12500) * 256 + threadIdx.x;
    const float* src;
    u16* dstp;
    int l;
    if (i < 32768)      { src = W1l; dstp = Wc1;          l = i; }
    else if (i < 65536) { src = W1r; dstp = Wc1 + 262144; l = i - 32768; }
    else if (i < 81920) { src = W2l; dstp = Wc2;          l = i - 65536; }
    else                { src = W2r; dstp = Wc2 + 131072; l = i - 81920; }
    const float4 a = ((const float4*)src)[2 * l];
    const float4 c = ((const float4*)src)[2 * l + 1];
    u16x8 o;
    o[0] = f2bf(a.x); o[1] = f2bf(a.y); o[2] = f2bf(a.z); o[3] = f2bf(a.w);
    o[4] = f2bf(c.x); o[5] = f2bf(c.y); o[6] = f2bf(c.z); o[7] = f2bf(c.w);
    ((u16x8*)dstp)[l] = o;
  } else {
    const int e = (b - 12884) * 256 + threadIdx.x;
    if (e < N_EDGES) atomicAdd(&degi[dst[e]], 1);
  }
}

// ---------------------------------------------------------------------------
// bf16 MFMA GEMM: [N_PAD,K] x [NX*128,K]^T. 1D grid, N-fast + XCD chunk
// swizzle; output split CT|CR (ld = NXH*128).
// 128x128 tile, BK=32, 256 thr (4 waves 2x2), 4x4 frags of 16x16x32.
// 3-deep counted-vmcnt pipeline (T4 depth arg, m218): the vmcnt(8) wait
// targets loads issued TWO iterations earlier (vs one at 2-deep) — the wait
// should be nearly free. Both-sides LDS chunk swizzle (T2, rule 21):
// linear gload dest, global source chunk (tid&3)^((tid>>3)&3), read slot
// fq^((fr>>1)&3) — measured 0 bank conflicts.
// Swapped-operand MFMA -> acc holds C^T frags -> 8B packed row-major stores.
// ---------------------------------------------------------------------------
template <int K, int NXL2, int NXH>
__global__ __launch_bounds__(256) void gemm_mfma(const u16* __restrict__ A,
                                                 const u16* __restrict__ B,
                                                 u16* __restrict__ CT,
                                                 u16* __restrict__ CR,
                                                 int nwg) {
  __shared__ __align__(16) u16 As[3][128 * 32];
  __shared__ __align__(16) u16 Bs[3][128 * 32];
  const int id = xcd_swizzle(blockIdx.x, nwg);
  const int bx = id & ((1 << NXL2) - 1);   // N tile (fast)
  const int by = id >> NXL2;               // M tile
  const int tid = threadIdx.x;
  const int lane = tid & 63;
  const int wave = tid >> 6;
  const int wr = (wave >> 1) * 64;
  const int wc = (wave & 1) * 64;
  const int fr = lane & 15;
  const int fq = lane >> 4;
  const size_t bm = (size_t)by * 128;
  const size_t bn = (size_t)bx * 128;

  // staging: linear LDS dest; global chunk pre-swizzled
  const int r0 = tid >> 2;                              // 0..63
  const int c0 = (((tid & 3) ^ ((tid >> 3) & 3)) * 8);  // swizzled k-chunk
  const u16* gA = A + (bm + r0) * K + c0;
  const u16* gB = B + (bn + r0) * K + c0;
  const size_t rstep = (size_t)64 * K;
  const int lofs = r0 * 32 + (tid & 3) * 8;             // linear dest
  constexpr int nt = K >> 5;
  static_assert(nt >= 3, "3-deep pipeline needs K >= 96");

  auto stage = [&](int b, int kt) {
    const int k0 = kt << 5;
    gload16(gA + k0, &As[b][lofs]);
    gload16(gA + rstep + k0, &As[b][lofs + 64 * 32]);
    gload16(gB + k0, &Bs[b][lofs]);
    gload16(gB + rstep + k0, &Bs[b][lofs + 64 * 32]);
  };

  f4v acc[4][4];
#pragma unroll
  for (int m = 0; m < 4; ++m)
#pragma unroll
    for (int n = 0; n < 4; ++n)
      acc[m][n] = f4v{0.f, 0.f, 0.f, 0.f};

  // read-side swizzle: slot = fq ^ kx, kx = (fr>>1)&3 (row-pair parity)
  const int kx = (fr >> 1) & 3;
  const int slot8 = (fq ^ kx) * 8;

  // prologue: tiles 0,1,2 in flight; wait for tile 0 (vmcnt(8) leaves 1,2)
  stage(0, 0);
  stage(1, 1);
  stage(2, 2);
  asm volatile("s_waitcnt vmcnt(8)" ::: "memory");
  __builtin_amdgcn_s_barrier();

  int cur = 0;
  for (int t = 0; t < nt; ++t) {
    const u16* curA = As[cur];
    const u16* curB = Bs[cur];
    s8v af[4], bf_[4];
#pragma unroll
    for (int m = 0; m < 4; ++m)
      af[m] = *(const s8v*)(curA + (wr + m * 16 + fr) * 32 + slot8);
#pragma unroll
    for (int n = 0; n < 4; ++n)
      bf_[n] = *(const s8v*)(curB + (wc + n * 16 + fr) * 32 + slot8);
#pragma unroll
    for (int m = 0; m < 4; ++m)
#pragma unroll
      for (int n = 0; n < 4; ++n)
        acc[m][n] = __builtin_amdgcn_mfma_f32_16x16x32_bf16(bf_[n], af[m],
                                                            acc[m][n], 0, 0, 0);
    if (t == nt - 1) break;
    __builtin_amdgcn_s_barrier();  // all waves done ds_reading buf[cur]
    if (t + 3 < nt) {
      stage(cur, t + 3);           // refill just-freed buffer
      // outstanding: t+2 (4) + t+3 (4); wait til <=8 ensures t+1 landed
      asm volatile("s_waitcnt vmcnt(8)" ::: "memory");
    } else if (t + 2 < nt) {
      // outstanding: up to t+1 (4) + t+2 (4); <=4 ensures t+1 landed
      asm volatile("s_waitcnt vmcnt(4)" ::: "memory");
    } else {
      asm volatile("s_waitcnt vmcnt(0)" ::: "memory");  // final drain
    }
    __builtin_amdgcn_s_barrier();
    cur = (cur == 2) ? 0 : cur + 1;
  }

  // epilogue (swapped layout): row = bm+wr+m*16+fr, col = cn0+n*16+fq*4+i
  u16* Cb = (bx < NXH) ? CT : CR;
  constexpr int ldc = NXH * 128;
  const size_t cn0 = (size_t)(bx - (bx >= NXH ? NXH : 0)) * 128 + wc;
#pragma unroll
  for (int m = 0; m < 4; ++m) {
    const size_t row = bm + wr + m * 16 + fr;
#pragma unroll
    for (int n = 0; n < 4; ++n) {
      const size_t col = cn0 + n * 16 + fq * 4;
      u16x4 p;
#pragma unroll
      for (int i = 0; i < 4; ++i) p[i] = f2bf(acc[m][n][i]);
      *(u16x4*)(Cb + row * ldc + col) = p;
    }
  }
}

// ---------------------------------------------------------------------------
// CSR build: hierarchical scan + cursor fill (histogram lives in prep_kernel)
// ---------------------------------------------------------------------------
__device__ __forceinline__ int block_scan_excl(int v, int* total_out) {
  const int lane = threadIdx.x & 63;
  const int wid = threadIdx.x >> 6;
  int s = v;
#pragma unroll
  for (int off = 1; off < 64; off <<= 1) {
    const int t = __shfl_up(s, off);
    if (lane >= off) s += t;
  }
  __shared__ int wsum[4];
  if (lane == 63) wsum[wid] = s;
  __syncthreads();
  int base = 0;
#pragma unroll
  for (int w = 0; w < 4; ++w)
    if (w < wid) base += wsum[w];
  *total_out = wsum[0] + wsum[1] + wsum[2] + wsum[3];
  return base + s - v;
}

__global__ __launch_bounds__(256) void scan_blocks(const int* __restrict__ degi,
                                                   int* __restrict__ offs,
                                                   int* __restrict__ bsum, int n) {
  const int gid = blockIdx.x * 256 + threadIdx.x;
  const int v = (gid < n) ? degi[gid] : 0;
  int total;
  const int excl = block_scan_excl(v, &total);
  if (gid < n) offs[gid] = excl;
  if (threadIdx.x == 0) bsum[blockIdx.x] = total;
}

__global__ __launch_bounds__(256) void scan_bsums(int* __restrict__ bsum, int nb) {
  const int v = (threadIdx.x < nb) ? bsum[threadIdx.x] : 0;
  int total;
  const int excl = block_scan_excl(v, &total);
  if (threadIdx.x < nb) bsum[threadIdx.x] = excl;
}

__global__ __launch_bounds__(256) void add_base(int* __restrict__ offs,
                                                const int* __restrict__ bsum,
                                                int n, int nE) {
  const int gid = blockIdx.x * 256 + threadIdx.x;
  if (gid < n) offs[gid] += bsum[blockIdx.x];
  if (gid == 0) offs[n] = nE;
}

__global__ void fill_csr(const int* __restrict__ src, const int* __restrict__ dst,
                         const int* __restrict__ offs, int* __restrict__ cursor,
                         int* __restrict__ sorted_src, int nE) {
  const int e = blockIdx.x * 256 + threadIdx.x;
  if (e < nE) {
    const int d = dst[e];
    const int pos = offs[d] + atomicAdd(&cursor[d], 1);
    sorted_src[pos] = src[e];
  }
}

// ---------------------------------------------------------------------------
// h[n] = relu( mean_{e in CSR(n)} t[src_e] + bias + r[n] ), bf16 in/out,
// compact ld = D. D/8 lanes per node; 8-deep independent-load batches.
// ---------------------------------------------------------------------------
template <int D>
__global__ __launch_bounds__(256) void gather_combine(
    const u16* __restrict__ t, const u16* __restrict__ r,
    const float* __restrict__ bias, const int* __restrict__ offs,
    const int* __restrict__ ssrc, u16* __restrict__ hout) {
  constexpr int LPN = D / 8;
  const int node = (int)((blockIdx.x * 256u + threadIdx.x) / LPN);
  if (node >= N_NODES) return;
  const int o = (int)(threadIdx.x % LPN) * 8;
  const int beg = offs[node], end = offs[node + 1];
  float a[8] = {0.f, 0.f, 0.f, 0.f, 0.f, 0.f, 0.f, 0.f};
  int e = beg;
  for (; e + 7 < end; e += 8) {
    u16x8 v[8];
#pragma unroll
    for (int q = 0; q < 8; ++q)
      v[q] = *(const u16x8*)(t + (size_t)ssrc[e + q] * D + o);
#pragma unroll
    for (int j = 0; j < 8; ++j)
      a[j] += ((bf2f(v[0][j]) + bf2f(v[1][j])) + (bf2f(v[2][j]) + bf2f(v[3][j]))) +
              ((bf2f(v[4][j]) + bf2f(v[5][j])) + (bf2f(v[6][j]) + bf2f(v[7][j])));
  }
  if (e + 3 < end) {
    u16x8 v[4];
#pragma unroll
    for (int q = 0; q < 4; ++q)
      v[q] = *(const u16x8*)(t + (size_t)ssrc[e + q] * D + o);
#pragma unroll
    for (int j = 0; j < 8; ++j)
      a[j] += (bf2f(v[0][j]) + bf2f(v[1][j])) + (bf2f(v[2][j]) + bf2f(v[3][j]));
    e += 4;
  }
  for (; e < end; ++e) {
    const u16x8 v0 = *(const u16x8*)(t + (size_t)ssrc[e] * D + o);
#pragma unroll
    for (int j = 0; j < 8; ++j) a[j] += bf2f(v0[j]);
  }
  const float invd = 1.0f / fmaxf((float)(end - beg), 1.0f);
  const u16x8 rv = *(const u16x8*)(r + (size_t)node * D + o);
  u16x8 ov;
#pragma unroll
  for (int j = 0; j < 8; ++j)
    ov[j] = f2bf(fmaxf(fmaf(a[j], invd, bias[o + j] + bf2f(rv[j])), 0.f));
  *(u16x8*)(hout + (size_t)node * D + o) = ov;
}

// ---------------------------------------------------------------------------
// Fused pool + FC + log_softmax (batch sorted -> contiguous node ranges)
// h is bf16 [N_NODES, HID2]
// ---------------------------------------------------------------------------
__global__ __launch_bounds__(256) void pool_final(const u16* __restrict__ h,
                                                  const int* __restrict__ batch,
                                                  const float* __restrict__ Wfc,
                                                  const float* __restrict__ bfc,
                                                  float* __restrict__ out, int nNodes) {
  const int g = blockIdx.x;
  __shared__ int sbeg, send;
  if (threadIdx.x == 0) {
    int lo = 0, hi = nNodes;
    while (lo < hi) { const int mid = (lo + hi) >> 1; if (batch[mid] < g) lo = mid + 1; else hi = mid; }
    sbeg = lo;
    hi = nNodes;
    while (lo < hi) { const int mid = (lo + hi) >> 1; if (batch[mid] < g + 1) lo = mid + 1; else hi = mid; }
    send = lo;
  }
  __syncthreads();
  const int t = threadIdx.x;
  float s = 0.f;
  for (int row = sbeg; row < send; ++row) s += bf2f(h[(size_t)row * HID2 + t]);
  const float cnt = fmaxf((float)(send - sbeg), 1.0f);
  const float p = s / cnt;
  float d0 = p * Wfc[t];
  float d1 = p * Wfc[HID2 + t];
#pragma unroll
  for (int off = 32; off > 0; off >>= 1) {
    d0 += __shfl_down(d0, off);
    d1 += __shfl_down(d1, off);
  }
  __shared__ float r0[4], r1[4];
  const int wid = t >> 6, lane = t & 63;
  if (lane == 0) { r0[wid] = d0; r1[wid] = d1; }
  __syncthreads();
  if (t == 0) {
    const float l0 = r0[0] + r0[1] + r0[2] + r0[3] + bfc[0];
    const float l1 = r1[0] + r1[1] + r1[2] + r1[3] + bfc[1];
    const float m = fmaxf(l0, l1);
    const float lse = m + logf(expf(l0 - m) + expf(l1 - m));
    out[g * 2 + 0] = l0 - lse;
    out[g * 2 + 1] = l1 - lse;
  }
}

extern "C" void kernel_launch(void* const* d_in, const int* in_sizes, int n_in,
                              void* d_out, int out_size, void* d_ws, size_t ws_size,
                              hipStream_t stream) {
  (void)in_sizes; (void)n_in; (void)out_size; (void)ws_size;
  const float* x   = (const float*)d_in[0];
  const int* eidx  = (const int*)d_in[1];
  const int* batch = (const int*)d_in[2];
  const float* W1l = (const float*)d_in[3];
  const float* b1  = (const float*)d_in[4];
  const float* W1r = (const float*)d_in[5];
  const float* W2l = (const float*)d_in[6];
  const float* b2  = (const float*)d_in[7];
  const float* W2r = (const float*)d_in[8];
  const float* Wfc = (const float*)d_in[9];
  const float* bfc = (const float*)d_in[10];
  float* out = (float*)d_out;
  const int* src = eidx;
  const int* dst = eidx + N_EDGES;

  char* ws = (char*)d_ws;
  size_t off = 0;
  auto alloc = [&](size_t bytes) {
    char* p = ws + off;
    off += (bytes + 255) & ~(size_t)255;
    return p;
  };
  u16* bufT = (u16*)alloc((size_t)N_PAD * 512 * 2);  // t1; reused as t2 (ld 256)
  u16* bufR = (u16*)alloc((size_t)N_PAD * 512 * 2);  // r1; reused as r2 (ld 256)
  u16* bufX = (u16*)alloc((size_t)N_PAD * 512 * 2);  // x bf16
  u16* h1   = (u16*)alloc((size_t)N_PAD * 512 * 2);
  u16* h2   = (u16*)alloc((size_t)N_NODES * 256 * 2);
  u16* Wc1  = (u16*)alloc((size_t)1024 * 512 * 2);
  u16* Wc2  = (u16*)alloc((size_t)512 * 512 * 2);
  int* degi   = (int*)alloc((size_t)N_NODES * 4);    // 200192 B reserved
  int* cursor = (int*)alloc((size_t)N_NODES * 4);    // adjacent to degi
  int* offs       = (int*)alloc((size_t)(N_NODES + 1) * 4);
  int* sorted_src = (int*)alloc((size_t)N_EDGES * 4);
  int* bsum       = (int*)alloc((size_t)SCAN_BLOCKS * 4);

  // ---- prep: zero degi+cursor, then {cvt_x | cvt_weights | deg_hist} ----
  hipMemsetAsync(degi, 0, 200192 + (size_t)N_NODES * 4, stream);
  prep_kernel<<<14447, 256, 0, stream>>>(x, bufX, W1l, W1r, W2l, W2r,
                                         Wc1, Wc2, dst, degi);

  // ---- CSR scan + fill ----
  scan_blocks<<<SCAN_BLOCKS, 256, 0, stream>>>(degi, offs, bsum, N_NODES);
  scan_bsums<<<1, 256, 0, stream>>>(bsum, SCAN_BLOCKS);
  add_base<<<SCAN_BLOCKS, 256, 0, stream>>>(offs, bsum, N_NODES, N_EDGES);
  fill_csr<<<(N_EDGES + 255) / 256, 256, 0, stream>>>(src, dst, offs, cursor,
                                                      sorted_src, N_EDGES);

  // ---- layer 1: [N_PAD,512] x [1024,512]^T -> t1 | r1 (each [N_PAD,512]) ----
  {
    const int nwg = (N_PAD / 128) * 8;  // 3128
    gemm_mfma<IN_DIM, 3, 4><<<nwg, 256, 0, stream>>>(bufX, Wc1, bufT, bufR, nwg);
  }
  gather_combine<HID><<<(N_NODES + 3) / 4, 256, 0, stream>>>(
      bufT, bufR, b1, offs, sorted_src, h1);

  // ---- layer 2: [N_PAD,512] x [512,512]^T -> t2 | r2 (each [N_PAD,256]) ----
  {
    const int nwg = (N_PAD / 128) * 4;  // 1564
    gemm_mfma<HID, 2, 2><<<nwg, 256, 0, stream>>>(h1, Wc2, bufT, bufR, nwg);
  }
  gather_combine<HID2><<<(N_NODES + 7) / 8, 256, 0, stream>>>(
      bufT, bufR, b2, offs, sorted_src, h2);

  // ---- pool + fc + log_softmax ----
  pool_final<<<NUM_GRAPHS, 256, 0, stream>>>(h2, batch, Wfc, bfc, out, N_NODES);
}